// Round 11
// baseline (1300.187 us; speedup 1.0000x reference)
//
#include <hip/hip_runtime.h>

typedef unsigned short u16;
typedef unsigned int u32;
typedef __attribute__((ext_vector_type(8))) short bf16x8;
typedef __attribute__((ext_vector_type(4))) float f32x4;

#define BATCH 4
#define SEQ 4096
#define DMODEL 1024
#define DINNER 1024
#define NPROJ 2176          // 2*DINNER + 2*DSTATE
#define MROWS (BATCH*SEQ)   // 16384
#define NCHUNK 64           // chunks per sequence
#define CLEN 64             // chunk length
#define NPAD 2304           // gemm1 N padded to 9*256

__device__ __forceinline__ float bf2f(u16 u) {
    union { u32 i; float f; } v; v.i = ((u32)u) << 16; return v.f;
}
__device__ __forceinline__ u16 f2bf(float f) {
    union { float f; u32 i; } v; v.f = f;
    u32 r = v.i + 0x7FFFu + ((v.i >> 16) & 1u);
    return (u16)(r >> 16);
}
__device__ __forceinline__ float silu_f(float x) { return x / (1.0f + expf(-x)); }

__device__ __forceinline__ void gload8f(const u16* p, float* o) {
    bf16x8 v = *(const bf16x8*)p;
    #pragma unroll
    for (int j = 0; j < 8; ++j) o[j] = bf2f((u16)v[j]);
}

// async global->LDS, 16B per lane; LDS dest = wave-uniform base + lane*16
__device__ __forceinline__ void ld_lds16(const u16* g, u16* l) {
    __builtin_amdgcn_global_load_lds(
        (const __attribute__((address_space(1))) u32*)g,
        (__attribute__((address_space(3))) u32*)l, 16, 0, 0);
}

// ---------------------------------------------------------------------------
// fp32 -> bf16 cast, 8 elems/thread
// ---------------------------------------------------------------------------
__global__ __launch_bounds__(256) void cast_f2b(
    const float* __restrict__ src, u16* __restrict__ dst, int n8)
{
    int i = blockIdx.x * 256 + threadIdx.x;
    if (i >= n8) return;
    size_t o = (size_t)i * 8;
    float4 a = *(const float4*)(src + o);
    float4 b = *(const float4*)(src + o + 4);
    u16 v[8] = {f2bf(a.x), f2bf(a.y), f2bf(a.z), f2bf(a.w),
                f2bf(b.x), f2bf(b.y), f2bf(b.z), f2bf(b.w)};
    *(bf16x8*)(dst + o) = *(bf16x8*)v;
}

// w1 cast with zero pad: src 2176x1024 fp32 -> dst 2304x1024 bf16 (rows>=2176 zero)
__global__ __launch_bounds__(256) void cast_w1p_k(
    const float* __restrict__ src, u16* __restrict__ dst)
{
    int i = blockIdx.x * 256 + threadIdx.x;      // chunk of 8; total NPAD*1024/8
    int row = i >> 7;                            // 128 chunks per row
    size_t o = (size_t)i * 8;
    u16 v[8];
    if (row < NPROJ) {
        float4 a = *(const float4*)(src + o);
        float4 b = *(const float4*)(src + o + 4);
        v[0]=f2bf(a.x); v[1]=f2bf(a.y); v[2]=f2bf(a.z); v[3]=f2bf(a.w);
        v[4]=f2bf(b.x); v[5]=f2bf(b.y); v[6]=f2bf(b.z); v[7]=f2bf(b.w);
    } else {
        #pragma unroll
        for (int j = 0; j < 8; ++j) v[j] = 0;
    }
    *(bf16x8*)(dst + o) = *(bf16x8*)v;
}

// ---------------------------------------------------------------------------
// Decay tables: l2a[n] = log2(a[n]); apw[t][n] = a[n]^t; ainv[t][n] = a[n]^-t
// ---------------------------------------------------------------------------
__global__ __launch_bounds__(256) void tables_k(
    const float* __restrict__ A_param, float* __restrict__ l2a_g,
    float* __restrict__ apw, float* __restrict__ ainv)
{
    __shared__ float l2s[64];
    int tid = threadIdx.x;
    if (tid < 64) {
        float v = -expf(A_param[tid]) * 1.44269504088896340736f;
        l2s[tid] = v;
        l2a_g[tid] = v;
    }
    __syncthreads();
    #pragma unroll
    for (int i = 0; i < 16; ++i) {
        int e = tid * 16 + i;          // e = t*64 + n
        int t = e >> 6, n = e & 63;
        float x = (float)t * l2s[n];
        apw[e]  = exp2f(x);
        ainv[e] = exp2f(-x);
    }
}

#define GK 1024

// ---------------------------------------------------------------------------
// gemm1 (BK=32 co-resident variant): 256x256 tile, 8 waves, LDS 64 KiB ->
// 2 blocks/CU (VGPR capped 128 via launch_bounds(512,4)).  Same quadrant/
// acc structure as the verified BK=64 kernel; each BK=64 tile splits into
// two BK=32 tiles -> bit-identical accumulation order.
//
// Calendar (traced r10; invariant: 2 A-chunks in flight at tile entry):
//   q0: stage B0(t+1) (->3)    q1: stage B1(t+1) (->4)
//   q2: stage A0(t+2) (->5), vmcnt(3)  drains A(t+1)  [read at q3]
//   q3: stage A1(t+2) (->4), vmcnt(2)  drains B(t+1)  [read next q0]
//   tails: t+2>=GNT: q2 vmcnt(2), q3 vmcnt(0); t=GNT-1: none.
// Swizzle (64B rows, 4 slots): write slot=(c&3)^((row>>1)&3) on global src;
// read XOR quad^((l16>>1)&3) -> 8 bank-groups x 2 lanes = 2-way (free).
// ---------------------------------------------------------------------------
#define GNT32 32
__global__ __launch_bounds__(512, 4) void gemm1bk32_k(
    const u16* __restrict__ A, const u16* __restrict__ B, u16* __restrict__ C)
{
    __shared__ u16 lds[32768];   // 64 KiB: A 2buf x 256x32 @0; B same @16384

    const int bid = blockIdx.x;                     // 576 = 8*72
    const int swz = (bid & 7) * 72 + (bid >> 3);
    const int bm = swz / 9, bn = swz % 9;
    const int m0 = bm * 256, n0 = bn * 256;

    const int tid = threadIdx.x;
    const int wid = tid >> 6, lane = tid & 63;
    const int wm = wid >> 2, wn = wid & 3;
    const int quad = lane >> 4, l16 = lane & 15;
    const int s32 = (quad ^ ((l16 >> 1) & 3)) * 8;  // read-side slot (u16 units)

    u16* L = lds;
    const u16* Ab = A + (size_t)m0 * GK;
    const u16* Bb = B + (size_t)n0 * GK;

    // stage one 128x32 half-tile: 512 thr x 1 chunk x 16B; linear LDS dest,
    // inverse-swizzled global source
    auto stage = [&](const u16* gbase, u16* ldsb) {
        int row = tid >> 2, slot = (tid & 3) ^ ((row >> 1) & 3);
        ld_lds16(gbase + (size_t)row * GK + slot * 8,
                 ldsb + ((tid & ~63) << 3));
    };
    auto rdfrag = [&](const u16* base, int rh) -> bf16x8 {
        return *(const bf16x8*)(base + rh * 32 + s32);
    };

    bf16x8 aLo[4], aHi[4], bLo[2], bHi[2];
    f32x4 acc[8][4] = {};

    // ---- prologue: tile0 fully + both A halves of tile1 in flight (6 chunks)
    stage(Ab,                 L);                   // A0 t0
    stage(Ab + 128 * GK,      L + 4096);            // A1 t0
    stage(Bb,                 L + 16384);           // B0 t0
    stage(Bb + 128 * GK,      L + 20480);           // B1 t0
    stage(Ab + 32,            L + 8192);            // A0 t1 -> buf1
    stage(Ab + 128 * GK + 32, L + 12288);           // A1 t1 -> buf1
    asm volatile("s_waitcnt vmcnt(2)" ::: "memory");   // tile0 landed
    __builtin_amdgcn_s_barrier();
    {
        const u16* Ard = L + wm * 4096;
        #pragma unroll
        for (int i = 0; i < 4; ++i)
            aLo[i] = rdfrag(Ard, i * 16 + l16);
    }

    for (int t = 0; t < GNT32; ++t) {
        const int cb = t & 1;
        u16* Acur = L + cb * 8192;
        u16* Anxt = L + (cb ^ 1) * 8192;
        u16* Bnxt = L + 16384 + (cb ^ 1) * 8192;
        const u16* ArdC = Acur + wm * 4096;
        const u16* ArdN = Anxt + wm * 4096;
        const u16* BrdC = L + 16384 + cb * 8192 + (wn >> 1) * 4096;
        const int brh = (wn & 1) * 64;

        // ---------------- q0: (lo-A, lo-B) ----------------
        #pragma unroll
        for (int j = 0; j < 2; ++j)
            bLo[j] = rdfrag(BrdC, brh + j * 16 + l16);
        if (t + 1 < GNT32) stage(Bb + (t + 1) * 32, Bnxt);          // B0(t+1)
        __builtin_amdgcn_s_barrier();
        asm volatile("s_waitcnt lgkmcnt(0)" ::: "memory");
        __builtin_amdgcn_s_setprio(1);
        #pragma unroll
        for (int i = 0; i < 4; ++i)
            #pragma unroll
            for (int j = 0; j < 2; ++j)
                acc[i][j] = __builtin_amdgcn_mfma_f32_16x16x32_bf16(
                    aLo[i], bLo[j], acc[i][j], 0, 0, 0);
        __builtin_amdgcn_s_setprio(0);
        __builtin_amdgcn_s_barrier();

        // ---------------- q1: (lo-A, hi-B) ----------------
        #pragma unroll
        for (int j = 0; j < 2; ++j)
            bHi[j] = rdfrag(BrdC, brh + 32 + j * 16 + l16);
        if (t + 1 < GNT32) stage(Bb + 128 * GK + (t + 1) * 32, Bnxt + 4096); // B1(t+1)
        __builtin_amdgcn_s_barrier();
        asm volatile("s_waitcnt lgkmcnt(0)" ::: "memory");
        __builtin_amdgcn_s_setprio(1);
        #pragma unroll
        for (int i = 0; i < 4; ++i)
            #pragma unroll
            for (int j = 0; j < 2; ++j)
                acc[i][2 + j] = __builtin_amdgcn_mfma_f32_16x16x32_bf16(
                    aLo[i], bHi[j], acc[i][2 + j], 0, 0, 0);
        __builtin_amdgcn_s_setprio(0);
        __builtin_amdgcn_s_barrier();

        // ---------------- q2: (hi-A, hi-B) ----------------
        #pragma unroll
        for (int i = 0; i < 4; ++i)
            aHi[i] = rdfrag(ArdC, 64 + i * 16 + l16);
        if (t + 2 < GNT32) stage(Ab + (t + 2) * 32, Acur);          // A0(t+2)
        if (t + 2 < GNT32)      { asm volatile("s_waitcnt vmcnt(3)" ::: "memory"); }
        else if (t + 1 < GNT32) { asm volatile("s_waitcnt vmcnt(2)" ::: "memory"); }
        __builtin_amdgcn_s_barrier();
        asm volatile("s_waitcnt lgkmcnt(0)" ::: "memory");
        __builtin_amdgcn_s_setprio(1);
        #pragma unroll
        for (int i = 0; i < 4; ++i)
            #pragma unroll
            for (int j = 0; j < 2; ++j)
                acc[4 + i][2 + j] = __builtin_amdgcn_mfma_f32_16x16x32_bf16(
                    aHi[i], bHi[j], acc[4 + i][2 + j], 0, 0, 0);
        __builtin_amdgcn_s_setprio(0);
        __builtin_amdgcn_s_barrier();

        // ---------------- q3: (hi-A, lo-B); prefetch next aLo ----------------
        if (t + 1 < GNT32) {
            #pragma unroll
            for (int i = 0; i < 4; ++i)
                aLo[i] = rdfrag(ArdN, i * 16 + l16);
        }
        if (t + 2 < GNT32) stage(Ab + 128 * GK + (t + 2) * 32, Acur + 4096); // A1(t+2)
        if (t + 2 < GNT32)      { asm volatile("s_waitcnt vmcnt(2)" ::: "memory"); }
        else if (t + 1 < GNT32) { asm volatile("s_waitcnt vmcnt(0)" ::: "memory"); }
        __builtin_amdgcn_s_barrier();
        asm volatile("s_waitcnt lgkmcnt(0)" ::: "memory");
        __builtin_amdgcn_s_setprio(1);
        #pragma unroll
        for (int i = 0; i < 4; ++i)
            #pragma unroll
            for (int j = 0; j < 2; ++j)
                acc[4 + i][j] = __builtin_amdgcn_mfma_f32_16x16x32_bf16(
                    aHi[i], bLo[j], acc[4 + i][j], 0, 0, 0);
        __builtin_amdgcn_s_setprio(0);
        __builtin_amdgcn_s_barrier();
    }

    // ---- epilogue: two-pass [128][256] u16 LDS transpose (fits 64 KiB) ----
    __syncthreads();
    {
        u16* eld = lds;          // viewed as [128][256] bf16
        #pragma unroll
        for (int h = 0; h < 2; ++h) {
            if (wm == h) {
                #pragma unroll
                for (int i = 0; i < 8; ++i)
                    #pragma unroll
                    for (int j = 0; j < 4; ++j)
                        #pragma unroll
                        for (int r = 0; r < 4; ++r)
                            eld[(size_t)(i * 16 + quad * 4 + r) * 256 +
                                wn * 64 + j * 16 + l16] = f2bf(acc[i][j][r]);
            }
            __syncthreads();
            #pragma unroll
            for (int rep = 0; rep < 8; ++rep) {
                int cc = rep * 512 + tid;
                int row = cc >> 5, c8 = (cc & 31) * 8;
                if (n0 + c8 < NPROJ)
                    *(bf16x8*)(C + (size_t)(m0 + h * 128 + row) * NPROJ + n0 + c8) =
                        *(const bf16x8*)(eld + (size_t)row * 256 + c8);
            }
            __syncthreads();
        }
    }
}

// ---------------------------------------------------------------------------
// gemm2: 8-phase 256x256 BK=64 NT GEMM (verified round-3 calendar) — UNCHANGED.
// ---------------------------------------------------------------------------
#define GNT 16   // K tiles of 64

template<typename TO, int GN, int NV, int LDC>
__global__ __launch_bounds__(512, 1) void gemm8p_k(
    const u16* __restrict__ A, const u16* __restrict__ B, TO* __restrict__ C)
{
    __shared__ u16 lds[65536];   // 128 KiB: A[2buf][2half][128*64] then B same

    const int cpx = (GN * 64) >> 3;
    const int bid = blockIdx.x;
    const int swz = (bid & 7) * cpx + (bid >> 3);   // XCD swizzle (nwg%8==0)
    const int bm = swz / GN, bn = swz % GN;
    const int m0 = bm * 256, n0 = bn * 256;

    const int tid = threadIdx.x;
    const int wid = tid >> 6, lane = tid & 63;
    const int wm = wid >> 2, wn = wid & 3;
    const int quad = lane >> 4, l16 = lane & 15;
    const int xsw = (l16 & 7) << 3;                 // read-side XOR (u16 units)

    u16* L = lds;
    const u16* Ab = A + (size_t)m0 * GK;
    const u16* Bb = B + (size_t)n0 * GK;

    auto stage = [&](const u16* gbase, u16* ldsb) {
        {
            int c = tid;
            int row = c >> 3, slot = (c & 7) ^ (row & 7);
            ld_lds16(gbase + (size_t)row * GK + slot * 8,
                     ldsb + ((tid & ~63) << 3));
        }
        {
            int c = 512 + tid;
            int row = c >> 3, slot = (c & 7) ^ (row & 7);
            ld_lds16(gbase + (size_t)row * GK + slot * 8,
                     ldsb + ((512 + (tid & ~63)) << 3));
        }
    };
    auto rdfrag = [&](const u16* base, int rh, int kh) -> bf16x8 {
        return *(const bf16x8*)(base + rh * 64 + ((kh * 32 + quad * 8) ^ xsw));
    };

    bf16x8 aLo[4][2], aHi[4][2], bLo[2][2], bHi[2][2];
    f32x4 acc[8][4] = {};

    // ---- prologue: tile0 fully + both A halves of tile1 in flight
    stage(Ab,                     L);               // A0 t0
    stage(Ab + 128 * GK,          L + 8192);        // A1 t0
    stage(Bb,                     L + 32768);       // B0 t0
    stage(Bb + 128 * GK,          L + 40960);       // B1 t0
    stage(Ab + 64,                L + 16384);       // A0 t1 -> buf1
    stage(Ab + 128 * GK + 64,     L + 24576);       // A1 t1 -> buf1
    asm volatile("s_waitcnt vmcnt(4)" ::: "memory");   // tile0 landed
    __builtin_amdgcn_s_barrier();
    {
        const u16* Ard = L + wm * 8192;
        #pragma unroll
        for (int i = 0; i < 4; ++i)
            #pragma unroll
            for (int kh = 0; kh < 2; ++kh)
                aLo[i][kh] = rdfrag(Ard, i * 16 + l16, kh);
    }

    for (int t = 0; t < GNT; ++t) {
        const int cb = t & 1;
        u16* Acur = L + cb * 16384;
        u16* Anxt = L + (cb ^ 1) * 16384;
        u16* Bnxt = L + 32768 + (cb ^ 1) * 16384;
        const u16* ArdC = Acur + wm * 8192;
        const u16* ArdN = Anxt + wm * 8192;
        const u16* BrdC = L + 32768 + cb * 16384 + (wn >> 1) * 8192;
        const int brh = (wn & 1) * 64;

        // ---------------- q0: MFMA quadrant (lo, lo) ----------------
        #pragma unroll
        for (int j = 0; j < 2; ++j)
            #pragma unroll
            for (int kh = 0; kh < 2; ++kh)
                bLo[j][kh] = rdfrag(BrdC, brh + j * 16 + l16, kh);
        if (t + 1 < GNT) stage(Bb + (t + 1) * 64, Bnxt);            // B0(t+1)
        __builtin_amdgcn_s_barrier();
        asm volatile("s_waitcnt lgkmcnt(0)" ::: "memory");
        __builtin_amdgcn_s_setprio(1);
        #pragma unroll
        for (int kh = 0; kh < 2; ++kh)
            #pragma unroll
            for (int i = 0; i < 4; ++i)
                #pragma unroll
                for (int j = 0; j < 2; ++j)
                    acc[i][j] = __builtin_amdgcn_mfma_f32_16x16x32_bf16(
                        aLo[i][kh], bLo[j][kh], acc[i][j], 0, 0, 0);
        __builtin_amdgcn_s_setprio(0);
        __builtin_amdgcn_s_barrier();

        // ---------------- q1: (lo, hi) ----------------
        #pragma unroll
        for (int j = 0; j < 2; ++j)
            #pragma unroll
            for (int kh = 0; kh < 2; ++kh)
                bHi[j][kh] = rdfrag(BrdC, brh + 32 + j * 16 + l16, kh);
        if (t + 1 < GNT) stage(Bb + 128 * GK + (t + 1) * 64, Bnxt + 8192); // B1(t+1)
        __builtin_amdgcn_s_barrier();
        asm volatile("s_waitcnt lgkmcnt(0)" ::: "memory");
        __builtin_amdgcn_s_setprio(1);
        #pragma unroll
        for (int kh = 0; kh < 2; ++kh)
            #pragma unroll
            for (int i = 0; i < 4; ++i)
                #pragma unroll
                for (int j = 0; j < 2; ++j)
                    acc[i][2 + j] = __builtin_amdgcn_mfma_f32_16x16x32_bf16(
                        aLo[i][kh], bHi[j][kh], acc[i][2 + j], 0, 0, 0);
        __builtin_amdgcn_s_setprio(0);
        __builtin_amdgcn_s_barrier();

        // ---------------- q2: (hi, hi) ----------------
        #pragma unroll
        for (int i = 0; i < 4; ++i)
            #pragma unroll
            for (int kh = 0; kh < 2; ++kh)
                aHi[i][kh] = rdfrag(ArdC, 64 + i * 16 + l16, kh);
        if (t + 2 < GNT) stage(Ab + (t + 2) * 64, Acur);            // A0(t+2)
        if (t + 2 < GNT)      { asm volatile("s_waitcnt vmcnt(6)" ::: "memory"); }
        else if (t + 1 < GNT) { asm volatile("s_waitcnt vmcnt(4)" ::: "memory"); }
        __builtin_amdgcn_s_barrier();
        asm volatile("s_waitcnt lgkmcnt(0)" ::: "memory");
        __builtin_amdgcn_s_setprio(1);
        #pragma unroll
        for (int kh = 0; kh < 2; ++kh)
            #pragma unroll
            for (int i = 0; i < 4; ++i)
                #pragma unroll
                for (int j = 0; j < 2; ++j)
                    acc[4 + i][2 + j] = __builtin_amdgcn_mfma_f32_16x16x32_bf16(
                        aHi[i][kh], bHi[j][kh], acc[4 + i][2 + j], 0, 0, 0);
        __builtin_amdgcn_s_setprio(0);
        __builtin_amdgcn_s_barrier();

        // ---------------- q3: (hi, lo); prefetch next aLo ----------------
        if (t + 1 < GNT) {
            #pragma unroll
            for (int i = 0; i < 4; ++i)
                #pragma unroll
                for (int kh = 0; kh < 2; ++kh)
                    aLo[i][kh] = rdfrag(ArdN, i * 16 + l16, kh);
        }
        if (t + 2 < GNT) stage(Ab + 128 * GK + (t + 2) * 64, Acur + 8192); // A1(t+2)
        if (t + 2 < GNT)      { asm volatile("s_waitcnt vmcnt(4)" ::: "memory"); }
        else if (t + 1 < GNT) { asm volatile("s_waitcnt vmcnt(0)" ::: "memory"); }
        __builtin_amdgcn_s_barrier();
        asm volatile("s_waitcnt lgkmcnt(0)" ::: "memory");
        __builtin_amdgcn_s_setprio(1);
        #pragma unroll
        for (int kh = 0; kh < 2; ++kh)
            #pragma unroll
            for (int i = 0; i < 4; ++i)
                #pragma unroll
                for (int j = 0; j < 2; ++j)
                    acc[4 + i][j] = __builtin_amdgcn_mfma_f32_16x16x32_bf16(
                        aHi[i][kh], bLo[j][kh], acc[4 + i][j], 0, 0, 0);
        __builtin_amdgcn_s_setprio(0);
        __builtin_amdgcn_s_barrier();
    }

    // ---- epilogue: LDS transpose -> coalesced stores ----
    __syncthreads();
    if constexpr (sizeof(TO) == 2) {
        u16* eld = lds;          // viewed as [256][256] bf16
        #pragma unroll
        for (int i = 0; i < 8; ++i)
            #pragma unroll
            for (int j = 0; j < 4; ++j)
                #pragma unroll
                for (int r = 0; r < 4; ++r)
                    eld[(size_t)(wm * 128 + i * 16 + quad * 4 + r) * 256 +
                        wn * 64 + j * 16 + l16] = f2bf(acc[i][j][r]);
        __syncthreads();
        #pragma unroll
        for (int rep = 0; rep < 16; ++rep) {
            int cc = rep * 512 + tid;
            int row = cc >> 5, c8 = (cc & 31) * 8;
            if (n0 + c8 < NV)
                *(bf16x8*)(C + (size_t)(m0 + row) * LDC + n0 + c8) =
                    *(const bf16x8*)(eld + (size_t)row * 256 + c8);
        }
    } else {
        float* eldf = (float*)lds;   // [128][256] fp32, two passes
        #pragma unroll
        for (int h = 0; h < 2; ++h) {
            if (wm == h) {
                #pragma unroll
                for (int i = 0; i < 8; ++i)
                    #pragma unroll
                    for (int j = 0; j < 4; ++j)
                        #pragma unroll
                        for (int r = 0; r < 4; ++r)
                            eldf[(size_t)(i * 16 + quad * 4 + r) * 256 +
                                 wn * 64 + j * 16 + l16] = acc[i][j][r];
            }
            __syncthreads();
            #pragma unroll
            for (int rep = 0; rep < 16; ++rep) {
                int cc = rep * 512 + tid;
                int row = cc >> 6, c4 = (cc & 63) * 4;
                *(float4*)(C + (size_t)(m0 + h * 128 + row) * LDC + n0 + c4) =
                    *(const float4*)(eldf + (size_t)row * 256 + c4);
            }
            __syncthreads();
        }
    }
}

// ---------------------------------------------------------------------------
// Pass A: intra-chunk SSD with fused causal conv (K=4) + bias + SiLU on the
// X-staging path.  Y -> separate yout buffer (xBC x-cols stay read-only).
// Grid (dg=16, c=64, b=4); 256 threads, 4 waves.  S output bf16.
// ---------------------------------------------------------------------------
__global__ __launch_bounds__(256) void ssd_intra_k(
    const float* __restrict__ conv_w, const float* __restrict__ conv_b,
    const u16* __restrict__ xBC, u16* __restrict__ yout,
    u16* __restrict__ Sh, const float* __restrict__ apw,
    const float* __restrict__ ainv)
{
    __shared__ u16 Pl[64][72];       // P[t][n] = C_t a^t
    __shared__ u16 Ql[64][72];       // Q[s][n] = B_s a^-s, then Ghi[t][s]
    __shared__ u16 Gl[64][72];       // Glo[t][s]
    __shared__ u16 Qt[64][72];       // Qt[n][s] = B_s a^{63-s}
    __shared__ u16 Xt[64][72];       // X^T [d][s]  (conv+silu applied)

    const int dg = blockIdx.x, c = blockIdx.y, b = blockIdx.z;
    const int dcol = dg * 64;
    const int l0 = c * CLEN;
    const int tid = threadIdx.x;
    const int w = tid >> 6, lane = tid & 63;
    const int quad = lane >> 4, l16 = lane & 15;
    const int tstrip = 16 * w;

    // stage B/C -> P, Q, Qt
    {
        const int st_t = tid >> 3, st_n8 = (tid & 7) * 8;
        #pragma unroll
        for (int rep = 0; rep < 2; ++rep) {
            int t = rep * 32 + st_t;
            size_t row = (size_t)(b * SEQ + l0 + t) * NPROJ;
            float Bv[8], Cv[8];
            gload8f(xBC + row + 2048 + st_n8, Bv);
            gload8f(xBC + row + 2112 + st_n8, Cv);
            float4 aw0 = *(const float4*)&apw[t * 64 + st_n8];
            float4 aw1 = *(const float4*)&apw[t * 64 + st_n8 + 4];
            float4 ai0 = *(const float4*)&ainv[t * 64 + st_n8];
            float4 ai1 = *(const float4*)&ainv[t * 64 + st_n8 + 4];
            float4 ar0 = *(const float4*)&apw[(63 - t) * 64 + st_n8];
            float4 ar1 = *(const float4*)&apw[(63 - t) * 64 + st_n8 + 4];
            float aw[8] = {aw0.x,aw0.y,aw0.z,aw0.w,aw1.x,aw1.y,aw1.z,aw1.w};
            float ai[8] = {ai0.x,ai0.y,ai0.z,ai0.w,ai1.x,ai1.y,ai1.z,ai1.w};
            float ar[8] = {ar0.x,ar0.y,ar0.z,ar0.w,ar1.x,ar1.y,ar1.z,ar1.w};
            u16 p8[8], q8[8];
            #pragma unroll
            for (int j = 0; j < 8; ++j) {
                p8[j] = f2bf(Cv[j] * aw[j]);
                q8[j] = f2bf(Bv[j] * ai[j]);
            }
            *(bf16x8*)&Pl[t][st_n8] = *(bf16x8*)p8;
            *(bf16x8*)&Ql[t][st_n8] = *(bf16x8*)q8;
            #pragma unroll
            for (int j = 0; j < 8; ++j)
                Qt[st_n8 + j][t] = f2bf(Bv[j] * ar[j]);
        }
    }
    // stage X transposed, computing conv+bias+SiLU on the fly from xBC x-cols
    {
        const int xt_d8 = (tid & 7) * 8;         // same channels both reps
        const int ch0 = dcol + xt_d8;
        float4 wv[8];
        #pragma unroll
        for (int j = 0; j < 8; ++j)
            wv[j] = *(const float4*)(conv_w + (ch0 + j) * 4);
        float bias[8];
        {
            float4 b0 = *(const float4*)(conv_b + ch0);
            float4 b1 = *(const float4*)(conv_b + ch0 + 4);
            bias[0]=b0.x; bias[1]=b0.y; bias[2]=b0.z; bias[3]=b0.w;
            bias[4]=b1.x; bias[5]=b1.y; bias[6]=b1.z; bias[7]=b1.w;
        }
        #pragma unroll
        for (int rep = 0; rep < 2; ++rep) {
            int xt_t = (tid >> 3) + rep * 32;    // 0..63
            float acc[8];
            #pragma unroll
            for (int j = 0; j < 8; ++j) acc[j] = bias[j];
            #pragma unroll
            for (int k = 0; k < 4; ++k) {
                int lt = l0 + xt_t - 3 + k;      // within-sequence index
                if (lt < 0) continue;
                float v[8];
                gload8f(xBC + (size_t)(b * SEQ + lt) * NPROJ + ch0, v);
                #pragma unroll
                for (int j = 0; j < 8; ++j) {
                    const float* wj = (const float*)&wv[j];
                    acc[j] += v[j] * wj[k];
                }
            }
            #pragma unroll
            for (int j = 0; j < 8; ++j)
                Xt[xt_d8 + j][xt_t] = f2bf(silu_f(acc[j]));
        }
    }
    __syncthreads();

    // ---- G = P Q^T (per wave: 16-t strip) ----
    bf16x8 af0 = *(const bf16x8*)&Pl[tstrip + l16][0  + quad * 8];
    bf16x8 af1 = *(const bf16x8*)&Pl[tstrip + l16][32 + quad * 8];
    f32x4 g[4] = {};
    #pragma unroll
    for (int j4 = 0; j4 < 4; ++j4) {
        bf16x8 b0 = *(const bf16x8*)&Ql[j4 * 16 + l16][0  + quad * 8];
        bf16x8 b1 = *(const bf16x8*)&Ql[j4 * 16 + l16][32 + quad * 8];
        g[j4] = __builtin_amdgcn_mfma_f32_16x16x32_bf16(af0, b0, g[j4], 0, 0, 0);
        g[j4] = __builtin_amdgcn_mfma_f32_16x16x32_bf16(af1, b1, g[j4], 0, 0, 0);
    }
    __syncthreads();

    // ---- mask (s<=t) + hi/lo split: Ghi->Ql, Glo->Gl ----
    #pragma unroll
    for (int j4 = 0; j4 < 4; ++j4) {
        #pragma unroll
        for (int r = 0; r < 4; ++r) {
            int t = tstrip + quad * 4 + r;
            int s = j4 * 16 + l16;
            float val = (s <= t) ? g[j4][r] : 0.f;
            u16 hi = f2bf(val);
            Ql[t][s] = hi;
            Gl[t][s] = f2bf(val - bf2f(hi));
        }
    }
    __syncthreads();

    // ---- Y strip [16t x 64d] and S strip [16n x 64d] ----
    bf16x8 gh0 = *(const bf16x8*)&Ql[tstrip + l16][0  + quad * 8];
    bf16x8 gh1 = *(const bf16x8*)&Ql[tstrip + l16][32 + quad * 8];
    bf16x8 gl0 = *(const bf16x8*)&Gl[tstrip + l16][0  + quad * 8];
    bf16x8 gl1 = *(const bf16x8*)&Gl[tstrip + l16][32 + quad * 8];
    bf16x8 qt0 = *(const bf16x8*)&Qt[tstrip + l16][0  + quad * 8];
    bf16x8 qt1 = *(const bf16x8*)&Qt[tstrip + l16][32 + quad * 8];

    #pragma unroll
    for (int dt = 0; dt < 4; ++dt) {
        bf16x8 x0 = *(const bf16x8*)&Xt[dt * 16 + l16][0  + quad * 8];
        bf16x8 x1 = *(const bf16x8*)&Xt[dt * 16 + l16][32 + quad * 8];
        f32x4 y = {};
        y = __builtin_amdgcn_mfma_f32_16x16x32_bf16(gh0, x0, y, 0, 0, 0);
        y = __builtin_amdgcn_mfma_f32_16x16x32_bf16(gh1, x1, y, 0, 0, 0);
        y = __builtin_amdgcn_mfma_f32_16x16x32_bf16(gl0, x0, y, 0, 0, 0);
        y = __builtin_amdgcn_mfma_f32_16x16x32_bf16(gl1, x1, y, 0, 0, 0);
        f32x4 s4 = {};
        s4 = __builtin_amdgcn_mfma_f32_16x16x32_bf16(qt0, x0, s4, 0, 0, 0);
        s4 = __builtin_amdgcn_mfma_f32_16x16x32_bf16(qt1, x1, s4, 0, 0, 0);
        #pragma unroll
        for (int r = 0; r < 4; ++r) {
            int t = tstrip + quad * 4 + r;       // y row -> separate Y buffer
            yout[(size_t)(b * SEQ + l0 + t) * DINNER + dcol + dt * 16 + l16] = f2bf(y[r]);
            int n = tstrip + quad * 4 + r;       // s row
            Sh[((size_t)((b * NCHUNK + c) * 64 + n)) * 1024 + dcol + dt * 16 + l16] = f2bf(s4[r]);
        }
    }
}

// ---------------------------------------------------------------------------
// Pass B: inter-chunk state scan, in place on Sh (bf16, fp32 carry).
// ---------------------------------------------------------------------------
__global__ __launch_bounds__(256) void state_scan_k(
    u16* __restrict__ Sh, const float* __restrict__ l2a)
{
    int gid = blockIdx.x * 256 + threadIdx.x;    // 262144 total
    int b = gid >> 16, r = gid & 65535, n = r >> 10;
    float a64 = exp2f(64.f * l2a[n]);
    float v = 0.f;
    size_t base = ((size_t)b << 22) + r;
    for (int c = 0; c < NCHUNK; ++c) {
        size_t addr = base + ((size_t)c << 16);
        float s = bf2f(Sh[addr]);
        Sh[addr] = f2bf(v);
        v = fmaf(v, a64, s);
    }
}

// ---------------------------------------------------------------------------
// Pass C: inter-chunk correction, RMW on Y buffer (pitch DINNER).
// Grid (dg=16, c=64, b=4); 256 threads, 4 waves.
// ---------------------------------------------------------------------------
__global__ __launch_bounds__(256) void ssd_inter_k(
    u16* __restrict__ Y, const u16* __restrict__ xBC,
    const u16* __restrict__ Sh, const float* __restrict__ apw,
    const float* __restrict__ l2a)
{
    __shared__ u16 Pl[64][72];       // P[t][n]
    __shared__ u16 Vt[64][72];       // (a*V)[d][n]

    const int dg = blockIdx.x, c = blockIdx.y, b = blockIdx.z;
    const int dcol = dg * 64;
    const int l0 = c * CLEN;
    const int tid = threadIdx.x;
    const int w = tid >> 6, lane = tid & 63;
    const int quad = lane >> 4, l16 = lane & 15;
    const int tstrip = 16 * w;

    // stage P
    {
        const int st_t = tid >> 3, st_n8 = (tid & 7) * 8;
        #pragma unroll
        for (int rep = 0; rep < 2; ++rep) {
            int t = rep * 32 + st_t;
            float Cv[8];
            gload8f(xBC + (size_t)(b * SEQ + l0 + t) * NPROJ + 2112 + st_n8, Cv);
            float4 aw0 = *(const float4*)&apw[t * 64 + st_n8];
            float4 aw1 = *(const float4*)&apw[t * 64 + st_n8 + 4];
            float aw[8] = {aw0.x,aw0.y,aw0.z,aw0.w,aw1.x,aw1.y,aw1.z,aw1.w};
            u16 p8[8];
            #pragma unroll
            for (int j = 0; j < 8; ++j) p8[j] = f2bf(Cv[j] * aw[j]);
            *(bf16x8*)&Pl[t][st_n8] = *(bf16x8*)p8;
        }
    }
    // stage aV transposed (bf16 Sh read, vector 16B)
    {
        #pragma unroll
        for (int rep = 0; rep < 2; ++rep) {
            int idx = rep * 256 + tid;          // 0..511
            int vn = idx >> 3, vd8 = (idx & 7) * 8;
            float an = exp2f(l2a[vn]);
            bf16x8 vv = *(const bf16x8*)&Sh[((size_t)((b * NCHUNK + c) * 64 + vn)) * 1024 + dcol + vd8];
            #pragma unroll
            for (int j = 0; j < 8; ++j) Vt[vd8 + j][vn] = f2bf(an * bf2f((u16)vv[j]));
        }
    }
    __syncthreads();

    bf16x8 af0 = *(const bf16x8*)&Pl[tstrip + l16][0  + quad * 8];
    bf16x8 af1 = *(const bf16x8*)&Pl[tstrip + l16][32 + quad * 8];
    #pragma unroll
    for (int dt = 0; dt < 4; ++dt) {
        bf16x8 hb0 = *(const bf16x8*)&Vt[dt * 16 + l16][0  + quad * 8];
        bf16x8 hb1 = *(const bf16x8*)&Vt[dt * 16 + l16][32 + quad * 8];
        f32x4 y = {};
        y = __builtin_amdgcn_mfma_f32_16x16x32_bf16(af0, hb0, y, 0, 0, 0);
        y = __builtin_amdgcn_mfma_f32_16x16x32_bf16(af1, hb1, y, 0, 0, 0);
        #pragma unroll
        for (int r = 0; r < 4; ++r) {
            int t = tstrip + quad * 4 + r;
            size_t addr = (size_t)(b * SEQ + l0 + t) * DINNER + dcol + dt * 16 + l16;
            Y[addr] = f2bf(bf2f(Y[addr]) + y[r]);
        }
    }
}

// ---------------------------------------------------------------------------
// Gate (y * silu(z)) + LayerNorm over 1024 channels.  One block per row.
// ---------------------------------------------------------------------------
__global__ __launch_bounds__(256) void gate_k(
    const u16* __restrict__ Y, const u16* __restrict__ xBC,
    const float* __restrict__ ln_w, const float* __restrict__ ln_b,
    u16* __restrict__ yn)
{
    __shared__ float r1[4], r2[4];
    const int row = blockIdx.x;
    const int tid = threadIdx.x;
    const int lane = tid & 63, wid = tid >> 6;

    float gv[4];
    {
        const ushort4 yv = *(const ushort4*)(Y + (size_t)row * DINNER + tid * 4);
        const ushort4 zv = *(const ushort4*)(xBC + (size_t)row * NPROJ + 1024 + tid * 4);
        gv[0] = bf2f(yv.x) * silu_f(bf2f(zv.x));
        gv[1] = bf2f(yv.y) * silu_f(bf2f(zv.y));
        gv[2] = bf2f(yv.z) * silu_f(bf2f(zv.z));
        gv[3] = bf2f(yv.w) * silu_f(bf2f(zv.w));
    }
    float ps = gv[0] + gv[1] + gv[2] + gv[3];
    float pq = gv[0]*gv[0] + gv[1]*gv[1] + gv[2]*gv[2] + gv[3]*gv[3];
    #pragma unroll
    for (int off = 1; off < 64; off <<= 1) {
        ps += __shfl_xor(ps, off);
        pq += __shfl_xor(pq, off);
    }
    if (lane == 0) { r1[wid] = ps; r2[wid] = pq; }
    __syncthreads();
    float ts = r1[0] + r1[1] + r1[2] + r1[3];
    float tq = r2[0] + r2[1] + r2[2] + r2[3];
    float mu = ts * (1.0f / DINNER);
    float var = tq * (1.0f / DINNER) - mu * mu;
    float inv = rsqrtf(var + 1e-5f);

    u16 outv[4];
    #pragma unroll
    for (int j = 0; j < 4; ++j) {
        int c = tid * 4 + j;
        float v = (gv[j] - mu) * inv * ln_w[c] + ln_b[c];
        outv[j] = f2bf(v);
    }
    *(ushort4*)(yn + (size_t)row * DINNER + tid * 4) = *(ushort4*)outv;
}

// ---------------------------------------------------------------------------
extern "C" void kernel_launch(void* const* d_in, const int* in_sizes, int n_in,
                              void* d_out, int out_size, void* d_ws, size_t ws_size,
                              hipStream_t stream) {
    const float* x   = (const float*)d_in[0];
    const float* w1  = (const float*)d_in[1];
    const float* cw  = (const float*)d_in[2];
    const float* cb  = (const float*)d_in[3];
    const float* ap  = (const float*)d_in[4];
    const float* lnw = (const float*)d_in[5];
    const float* lnb = (const float*)d_in[6];
    const float* w2  = (const float*)d_in[7];
    float* out = (float*)d_out;

    // ws layout (~107 MiB):
    u16* xBC   = (u16*)d_ws;                             // MROWS x 2176
    u16* xact  = xBC + (size_t)MROWS * NPROJ;            // MROWS x 1024
    u16* x_bf  = xact;                                   // gemm1 A; dead after gemm1,
                                                         // then reused as Y buffer
    u16* w2_bf = xact + (size_t)MROWS * DINNER;          // 1024x1024
    float* l2a  = (float*)(w2_bf + (size_t)DMODEL * DINNER);  // 64
    float* apw  = l2a + 64;                              // 64x64
    float* ainv = apw + 4096;                            // 64x64
    // w1p (padded weights, 4.7MB) then Sh (bf16 S/V, 33.5MB) park in d_out:
    // w1p dead after gemm1; Sh written by pass A, consumed by ssd_inter
    // before gemm2 overwrites d_out with the final output.
    u16* w1p = (u16*)d_out;                              // 2304x1024 bf16
    u16* Sh  = (u16*)d_out;                              // 4 x 64 x 64 x 1024 bf16

    cast_f2b<<<(MROWS * DMODEL / 8) / 256, 256, 0, stream>>>(x, x_bf, MROWS * DMODEL / 8);
    cast_w1p_k<<<(NPAD * DMODEL / 8) / 256, 256, 0, stream>>>(w1, w1p);
    cast_f2b<<<(DMODEL * DINNER / 8) / 256, 256, 0, stream>>>(w2, w2_bf, DMODEL * DINNER / 8);
    tables_k<<<1, 256, 0, stream>>>(ap, l2a, apw, ainv);

    gemm1bk32_k<<<9 * 64, 512, 0, stream>>>(x_bf, w1p, xBC);

    // conv fused into intra X-staging; Y -> xact (x_bf dead after gemm1)
    ssd_intra_k<<<dim3(16, NCHUNK, BATCH), 256, 0, stream>>>(cw, cb, xBC, xact, Sh, apw, ainv);
    state_scan_k<<<1024, 256, 0, stream>>>(Sh, l2a);
    ssd_inter_k<<<dim3(16, NCHUNK, BATCH), 256, 0, stream>>>(xact, xBC, Sh, apw, l2a);

    gate_k<<<MROWS, 256, 0, stream>>>(xact, xBC, lnw, lnb, xact);
    gemm8p_k<float, 4, DMODEL, DMODEL><<<4 * 64, 512, 0, stream>>>(xact, w2_bf, out);
}

// Round 12
// 385.601 us; speedup vs baseline: 3.3718x; 3.3718x over previous
//
#include <hip/hip_runtime.h>

typedef unsigned short u16;
typedef unsigned int u32;
typedef __attribute__((ext_vector_type(8))) short bf16x8;
typedef __attribute__((ext_vector_type(4))) float f32x4;

#define BATCH 4
#define SEQ 4096
#define DMODEL 1024
#define DINNER 1024
#define NPROJ 2176          // 2*DINNER + 2*DSTATE
#define MROWS (BATCH*SEQ)   // 16384
#define NCHUNK 64           // chunks per sequence
#define CLEN 64             // chunk length
#define NPAD 2304           // gemm1 N padded to 9*256

__device__ __forceinline__ float bf2f(u16 u) {
    union { u32 i; float f; } v; v.i = ((u32)u) << 16; return v.f;
}
__device__ __forceinline__ u16 f2bf(float f) {
    union { float f; u32 i; } v; v.f = f;
    u32 r = v.i + 0x7FFFu + ((v.i >> 16) & 1u);
    return (u16)(r >> 16);
}
__device__ __forceinline__ float silu_f(float x) { return x / (1.0f + expf(-x)); }

__device__ __forceinline__ void gload8f(const u16* p, float* o) {
    bf16x8 v = *(const bf16x8*)p;
    #pragma unroll
    for (int j = 0; j < 8; ++j) o[j] = bf2f((u16)v[j]);
}

// async global->LDS, 16B per lane; LDS dest = wave-uniform base + lane*16
__device__ __forceinline__ void ld_lds16(const u16* g, u16* l) {
    __builtin_amdgcn_global_load_lds(
        (const __attribute__((address_space(1))) u32*)g,
        (__attribute__((address_space(3))) u32*)l, 16, 0, 0);
}

// ---------------------------------------------------------------------------
// fp32 -> bf16 cast, 8 elems/thread
// ---------------------------------------------------------------------------
__global__ __launch_bounds__(256) void cast_f2b(
    const float* __restrict__ src, u16* __restrict__ dst, int n8)
{
    int i = blockIdx.x * 256 + threadIdx.x;
    if (i >= n8) return;
    size_t o = (size_t)i * 8;
    float4 a = *(const float4*)(src + o);
    float4 b = *(const float4*)(src + o + 4);
    u16 v[8] = {f2bf(a.x), f2bf(a.y), f2bf(a.z), f2bf(a.w),
                f2bf(b.x), f2bf(b.y), f2bf(b.z), f2bf(b.w)};
    *(bf16x8*)(dst + o) = *(bf16x8*)v;
}

// w1 cast with zero pad: src 2176x1024 fp32 -> dst 2304x1024 bf16 (rows>=2176 zero)
__global__ __launch_bounds__(256) void cast_w1p_k(
    const float* __restrict__ src, u16* __restrict__ dst)
{
    int i = blockIdx.x * 256 + threadIdx.x;      // chunk of 8; total NPAD*1024/8
    int row = i >> 7;                            // 128 chunks per row
    size_t o = (size_t)i * 8;
    u16 v[8];
    if (row < NPROJ) {
        float4 a = *(const float4*)(src + o);
        float4 b = *(const float4*)(src + o + 4);
        v[0]=f2bf(a.x); v[1]=f2bf(a.y); v[2]=f2bf(a.z); v[3]=f2bf(a.w);
        v[4]=f2bf(b.x); v[5]=f2bf(b.y); v[6]=f2bf(b.z); v[7]=f2bf(b.w);
    } else {
        #pragma unroll
        for (int j = 0; j < 8; ++j) v[j] = 0;
    }
    *(bf16x8*)(dst + o) = *(bf16x8*)v;
}

// ---------------------------------------------------------------------------
// Decay tables: l2a[n] = log2(a[n]); apw[t][n] = a[n]^t; ainv[t][n] = a[n]^-t
// ---------------------------------------------------------------------------
__global__ __launch_bounds__(256) void tables_k(
    const float* __restrict__ A_param, float* __restrict__ l2a_g,
    float* __restrict__ apw, float* __restrict__ ainv)
{
    __shared__ float l2s[64];
    int tid = threadIdx.x;
    if (tid < 64) {
        float v = -expf(A_param[tid]) * 1.44269504088896340736f;
        l2s[tid] = v;
        l2a_g[tid] = v;
    }
    __syncthreads();
    #pragma unroll
    for (int i = 0; i < 16; ++i) {
        int e = tid * 16 + i;          // e = t*64 + n
        int t = e >> 6, n = e & 63;
        float x = (float)t * l2s[n];
        apw[e]  = exp2f(x);
        ainv[e] = exp2f(-x);
    }
}

// ---------------------------------------------------------------------------
// 8-phase 256x256 NT GEMM (HK-style schedule in plain HIP).
// C[M,Npad] = A[M,1024] @ B[Npad,1024]^T, bf16 in, fp32 accum.
// Race-free uniform-vmcnt calendar (round-3) — UNCHANGED.
// ---------------------------------------------------------------------------
#define GK 1024
#define GNT 16   // K tiles of 64

template<typename TO, int GN, int NV, int LDC>
__global__ __launch_bounds__(512, 1) void gemm8p_k(
    const u16* __restrict__ A, const u16* __restrict__ B, TO* __restrict__ C)
{
    __shared__ u16 lds[65536];   // 128 KiB: A[2buf][2half][128*64] then B same

    const int cpx = (GN * 64) >> 3;
    const int bid = blockIdx.x;
    const int swz = (bid & 7) * cpx + (bid >> 3);   // XCD swizzle (nwg%8==0)
    const int bm = swz / GN, bn = swz % GN;
    const int m0 = bm * 256, n0 = bn * 256;

    const int tid = threadIdx.x;
    const int wid = tid >> 6, lane = tid & 63;
    const int wm = wid >> 2, wn = wid & 3;
    const int quad = lane >> 4, l16 = lane & 15;
    const int xsw = (l16 & 7) << 3;                 // read-side XOR (u16 units)

    u16* L = lds;
    const u16* Ab = A + (size_t)m0 * GK;
    const u16* Bb = B + (size_t)n0 * GK;

    auto stage = [&](const u16* gbase, u16* ldsb) {
        {
            int c = tid;
            int row = c >> 3, slot = (c & 7) ^ (row & 7);
            ld_lds16(gbase + (size_t)row * GK + slot * 8,
                     ldsb + ((tid & ~63) << 3));
        }
        {
            int c = 512 + tid;
            int row = c >> 3, slot = (c & 7) ^ (row & 7);
            ld_lds16(gbase + (size_t)row * GK + slot * 8,
                     ldsb + ((512 + (tid & ~63)) << 3));
        }
    };
    auto rdfrag = [&](const u16* base, int rh, int kh) -> bf16x8 {
        return *(const bf16x8*)(base + rh * 64 + ((kh * 32 + quad * 8) ^ xsw));
    };

    bf16x8 aLo[4][2], aHi[4][2], bLo[2][2], bHi[2][2];
    f32x4 acc[8][4] = {};

    // ---- prologue: tile0 fully + both A halves of tile1 in flight
    stage(Ab,                     L);               // A0 t0
    stage(Ab + 128 * GK,          L + 8192);        // A1 t0
    stage(Bb,                     L + 32768);       // B0 t0
    stage(Bb + 128 * GK,          L + 40960);       // B1 t0
    stage(Ab + 64,                L + 16384);       // A0 t1 -> buf1
    stage(Ab + 128 * GK + 64,     L + 24576);       // A1 t1 -> buf1
    asm volatile("s_waitcnt vmcnt(4)" ::: "memory");   // tile0 landed
    __builtin_amdgcn_s_barrier();
    {
        const u16* Ard = L + wm * 8192;
        #pragma unroll
        for (int i = 0; i < 4; ++i)
            #pragma unroll
            for (int kh = 0; kh < 2; ++kh)
                aLo[i][kh] = rdfrag(Ard, i * 16 + l16, kh);
    }

    for (int t = 0; t < GNT; ++t) {
        const int cb = t & 1;
        u16* Acur = L + cb * 16384;
        u16* Anxt = L + (cb ^ 1) * 16384;
        u16* Bnxt = L + 32768 + (cb ^ 1) * 16384;
        const u16* ArdC = Acur + wm * 8192;
        const u16* ArdN = Anxt + wm * 8192;
        const u16* BrdC = L + 32768 + cb * 16384 + (wn >> 1) * 8192;
        const int brh = (wn & 1) * 64;

        // ---------------- q0: MFMA quadrant (lo, lo) ----------------
        #pragma unroll
        for (int j = 0; j < 2; ++j)
            #pragma unroll
            for (int kh = 0; kh < 2; ++kh)
                bLo[j][kh] = rdfrag(BrdC, brh + j * 16 + l16, kh);
        if (t + 1 < GNT) stage(Bb + (t + 1) * 64, Bnxt);            // B0(t+1)
        __builtin_amdgcn_s_barrier();
        asm volatile("s_waitcnt lgkmcnt(0)" ::: "memory");
        __builtin_amdgcn_s_setprio(1);
        #pragma unroll
        for (int kh = 0; kh < 2; ++kh)
            #pragma unroll
            for (int i = 0; i < 4; ++i)
                #pragma unroll
                for (int j = 0; j < 2; ++j)
                    acc[i][j] = __builtin_amdgcn_mfma_f32_16x16x32_bf16(
                        aLo[i][kh], bLo[j][kh], acc[i][j], 0, 0, 0);
        __builtin_amdgcn_s_setprio(0);
        __builtin_amdgcn_s_barrier();

        // ---------------- q1: (lo, hi) ----------------
        #pragma unroll
        for (int j = 0; j < 2; ++j)
            #pragma unroll
            for (int kh = 0; kh < 2; ++kh)
                bHi[j][kh] = rdfrag(BrdC, brh + 32 + j * 16 + l16, kh);
        if (t + 1 < GNT) stage(Bb + 128 * GK + (t + 1) * 64, Bnxt + 8192); // B1(t+1)
        __builtin_amdgcn_s_barrier();
        asm volatile("s_waitcnt lgkmcnt(0)" ::: "memory");
        __builtin_amdgcn_s_setprio(1);
        #pragma unroll
        for (int kh = 0; kh < 2; ++kh)
            #pragma unroll
            for (int i = 0; i < 4; ++i)
                #pragma unroll
                for (int j = 0; j < 2; ++j)
                    acc[i][2 + j] = __builtin_amdgcn_mfma_f32_16x16x32_bf16(
                        aLo[i][kh], bHi[j][kh], acc[i][2 + j], 0, 0, 0);
        __builtin_amdgcn_s_setprio(0);
        __builtin_amdgcn_s_barrier();

        // ---------------- q2: (hi, hi) ----------------
        #pragma unroll
        for (int i = 0; i < 4; ++i)
            #pragma unroll
            for (int kh = 0; kh < 2; ++kh)
                aHi[i][kh] = rdfrag(ArdC, 64 + i * 16 + l16, kh);
        if (t + 2 < GNT) stage(Ab + (t + 2) * 64, Acur);            // A0(t+2)
        if (t + 2 < GNT)      { asm volatile("s_waitcnt vmcnt(6)" ::: "memory"); }
        else if (t + 1 < GNT) { asm volatile("s_waitcnt vmcnt(4)" ::: "memory"); }
        __builtin_amdgcn_s_barrier();
        asm volatile("s_waitcnt lgkmcnt(0)" ::: "memory");
        __builtin_amdgcn_s_setprio(1);
        #pragma unroll
        for (int kh = 0; kh < 2; ++kh)
            #pragma unroll
            for (int i = 0; i < 4; ++i)
                #pragma unroll
                for (int j = 0; j < 2; ++j)
                    acc[4 + i][2 + j] = __builtin_amdgcn_mfma_f32_16x16x32_bf16(
                        aHi[i][kh], bHi[j][kh], acc[4 + i][2 + j], 0, 0, 0);
        __builtin_amdgcn_s_setprio(0);
        __builtin_amdgcn_s_barrier();

        // ---------------- q3: (hi, lo); prefetch next aLo ----------------
        if (t + 1 < GNT) {
            #pragma unroll
            for (int i = 0; i < 4; ++i)
                #pragma unroll
                for (int kh = 0; kh < 2; ++kh)
                    aLo[i][kh] = rdfrag(ArdN, i * 16 + l16, kh);
        }
        if (t + 2 < GNT) stage(Ab + 128 * GK + (t + 2) * 64, Acur + 8192); // A1(t+2)
        if (t + 2 < GNT)      { asm volatile("s_waitcnt vmcnt(4)" ::: "memory"); }
        else if (t + 1 < GNT) { asm volatile("s_waitcnt vmcnt(0)" ::: "memory"); }
        __builtin_amdgcn_s_barrier();
        asm volatile("s_waitcnt lgkmcnt(0)" ::: "memory");
        __builtin_amdgcn_s_setprio(1);
        #pragma unroll
        for (int kh = 0; kh < 2; ++kh)
            #pragma unroll
            for (int i = 0; i < 4; ++i)
                #pragma unroll
                for (int j = 0; j < 2; ++j)
                    acc[4 + i][j] = __builtin_amdgcn_mfma_f32_16x16x32_bf16(
                        aHi[i][kh], bLo[j][kh], acc[4 + i][j], 0, 0, 0);
        __builtin_amdgcn_s_setprio(0);
        __builtin_amdgcn_s_barrier();
    }

    // ---- epilogue: LDS transpose -> coalesced stores ----
    __syncthreads();
    if constexpr (sizeof(TO) == 2) {
        u16* eld = lds;          // viewed as [256][256] bf16
        #pragma unroll
        for (int i = 0; i < 8; ++i)
            #pragma unroll
            for (int j = 0; j < 4; ++j)
                #pragma unroll
                for (int r = 0; r < 4; ++r)
                    eld[(size_t)(wm * 128 + i * 16 + quad * 4 + r) * 256 +
                        wn * 64 + j * 16 + l16] = f2bf(acc[i][j][r]);
        __syncthreads();
        #pragma unroll
        for (int rep = 0; rep < 16; ++rep) {
            int cc = rep * 512 + tid;
            int row = cc >> 5, c8 = (cc & 31) * 8;
            if (n0 + c8 < NV)
                *(bf16x8*)(C + (size_t)(m0 + row) * LDC + n0 + c8) =
                    *(const bf16x8*)(eld + (size_t)row * 256 + c8);
        }
    } else {
        float* eldf = (float*)lds;   // [128][256] fp32, two passes
        #pragma unroll
        for (int h = 0; h < 2; ++h) {
            if (wm == h) {
                #pragma unroll
                for (int i = 0; i < 8; ++i)
                    #pragma unroll
                    for (int j = 0; j < 4; ++j)
                        #pragma unroll
                        for (int r = 0; r < 4; ++r)
                            eldf[(size_t)(i * 16 + quad * 4 + r) * 256 +
                                 wn * 64 + j * 16 + l16] = acc[i][j][r];
            }
            __syncthreads();
            #pragma unroll
            for (int rep = 0; rep < 16; ++rep) {
                int cc = rep * 512 + tid;
                int row = cc >> 6, c4 = (cc & 63) * 4;
                *(float4*)(C + (size_t)(m0 + h * 128 + row) * LDC + n0 + c4) =
                    *(const float4*)(eldf + (size_t)row * 256 + c4);
            }
            __syncthreads();
        }
    }
}

// ---------------------------------------------------------------------------
// Pass A: intra-chunk SSD with fused causal conv (K=4) + bias + SiLU on the
// X-staging path.  Y -> separate yout buffer (xBC x-cols stay read-only).
// Grid (dg=16, c=64, b=4); 256 threads, 4 waves.  S output bf16.
// ---------------------------------------------------------------------------
__global__ __launch_bounds__(256) void ssd_intra_k(
    const float* __restrict__ conv_w, const float* __restrict__ conv_b,
    const u16* __restrict__ xBC, u16* __restrict__ yout,
    u16* __restrict__ Sh, const float* __restrict__ apw,
    const float* __restrict__ ainv)
{
    __shared__ u16 Pl[64][72];       // P[t][n] = C_t a^t
    __shared__ u16 Ql[64][72];       // Q[s][n] = B_s a^-s, then Ghi[t][s]
    __shared__ u16 Gl[64][72];       // Glo[t][s]
    __shared__ u16 Qt[64][72];       // Qt[n][s] = B_s a^{63-s}
    __shared__ u16 Xt[64][72];       // X^T [d][s]  (conv+silu applied)

    const int dg = blockIdx.x, c = blockIdx.y, b = blockIdx.z;
    const int dcol = dg * 64;
    const int l0 = c * CLEN;
    const int tid = threadIdx.x;
    const int w = tid >> 6, lane = tid & 63;
    const int quad = lane >> 4, l16 = lane & 15;
    const int tstrip = 16 * w;

    // stage B/C -> P, Q, Qt
    {
        const int st_t = tid >> 3, st_n8 = (tid & 7) * 8;
        #pragma unroll
        for (int rep = 0; rep < 2; ++rep) {
            int t = rep * 32 + st_t;
            size_t row = (size_t)(b * SEQ + l0 + t) * NPROJ;
            float Bv[8], Cv[8];
            gload8f(xBC + row + 2048 + st_n8, Bv);
            gload8f(xBC + row + 2112 + st_n8, Cv);
            float4 aw0 = *(const float4*)&apw[t * 64 + st_n8];
            float4 aw1 = *(const float4*)&apw[t * 64 + st_n8 + 4];
            float4 ai0 = *(const float4*)&ainv[t * 64 + st_n8];
            float4 ai1 = *(const float4*)&ainv[t * 64 + st_n8 + 4];
            float4 ar0 = *(const float4*)&apw[(63 - t) * 64 + st_n8];
            float4 ar1 = *(const float4*)&apw[(63 - t) * 64 + st_n8 + 4];
            float aw[8] = {aw0.x,aw0.y,aw0.z,aw0.w,aw1.x,aw1.y,aw1.z,aw1.w};
            float ai[8] = {ai0.x,ai0.y,ai0.z,ai0.w,ai1.x,ai1.y,ai1.z,ai1.w};
            float ar[8] = {ar0.x,ar0.y,ar0.z,ar0.w,ar1.x,ar1.y,ar1.z,ar1.w};
            u16 p8[8], q8[8];
            #pragma unroll
            for (int j = 0; j < 8; ++j) {
                p8[j] = f2bf(Cv[j] * aw[j]);
                q8[j] = f2bf(Bv[j] * ai[j]);
            }
            *(bf16x8*)&Pl[t][st_n8] = *(bf16x8*)p8;
            *(bf16x8*)&Ql[t][st_n8] = *(bf16x8*)q8;
            #pragma unroll
            for (int j = 0; j < 8; ++j)
                Qt[st_n8 + j][t] = f2bf(Bv[j] * ar[j]);
        }
    }
    // stage X transposed, computing conv+bias+SiLU on the fly from xBC x-cols
    {
        const int xt_d8 = (tid & 7) * 8;         // same channels both reps
        const int ch0 = dcol + xt_d8;
        float4 wv[8];
        #pragma unroll
        for (int j = 0; j < 8; ++j)
            wv[j] = *(const float4*)(conv_w + (ch0 + j) * 4);
        float bias[8];
        {
            float4 b0 = *(const float4*)(conv_b + ch0);
            float4 b1 = *(const float4*)(conv_b + ch0 + 4);
            bias[0]=b0.x; bias[1]=b0.y; bias[2]=b0.z; bias[3]=b0.w;
            bias[4]=b1.x; bias[5]=b1.y; bias[6]=b1.z; bias[7]=b1.w;
        }
        #pragma unroll
        for (int rep = 0; rep < 2; ++rep) {
            int xt_t = (tid >> 3) + rep * 32;    // 0..63
            float acc[8];
            #pragma unroll
            for (int j = 0; j < 8; ++j) acc[j] = bias[j];
            #pragma unroll
            for (int k = 0; k < 4; ++k) {
                int lt = l0 + xt_t - 3 + k;      // within-sequence index
                if (lt < 0) continue;
                float v[8];
                gload8f(xBC + (size_t)(b * SEQ + lt) * NPROJ + ch0, v);
                #pragma unroll
                for (int j = 0; j < 8; ++j) {
                    const float* wj = (const float*)&wv[j];
                    acc[j] += v[j] * wj[k];
                }
            }
            #pragma unroll
            for (int j = 0; j < 8; ++j)
                Xt[xt_d8 + j][xt_t] = f2bf(silu_f(acc[j]));
        }
    }
    __syncthreads();

    // ---- G = P Q^T (per wave: 16-t strip) ----
    bf16x8 af0 = *(const bf16x8*)&Pl[tstrip + l16][0  + quad * 8];
    bf16x8 af1 = *(const bf16x8*)&Pl[tstrip + l16][32 + quad * 8];
    f32x4 g[4] = {};
    #pragma unroll
    for (int j4 = 0; j4 < 4; ++j4) {
        bf16x8 b0 = *(const bf16x8*)&Ql[j4 * 16 + l16][0  + quad * 8];
        bf16x8 b1 = *(const bf16x8*)&Ql[j4 * 16 + l16][32 + quad * 8];
        g[j4] = __builtin_amdgcn_mfma_f32_16x16x32_bf16(af0, b0, g[j4], 0, 0, 0);
        g[j4] = __builtin_amdgcn_mfma_f32_16x16x32_bf16(af1, b1, g[j4], 0, 0, 0);
    }
    __syncthreads();

    // ---- mask (s<=t) + hi/lo split: Ghi->Ql, Glo->Gl ----
    #pragma unroll
    for (int j4 = 0; j4 < 4; ++j4) {
        #pragma unroll
        for (int r = 0; r < 4; ++r) {
            int t = tstrip + quad * 4 + r;
            int s = j4 * 16 + l16;
            float val = (s <= t) ? g[j4][r] : 0.f;
            u16 hi = f2bf(val);
            Ql[t][s] = hi;
            Gl[t][s] = f2bf(val - bf2f(hi));
        }
    }
    __syncthreads();

    // ---- Y strip [16t x 64d] and S strip [16n x 64d] ----
    bf16x8 gh0 = *(const bf16x8*)&Ql[tstrip + l16][0  + quad * 8];
    bf16x8 gh1 = *(const bf16x8*)&Ql[tstrip + l16][32 + quad * 8];
    bf16x8 gl0 = *(const bf16x8*)&Gl[tstrip + l16][0  + quad * 8];
    bf16x8 gl1 = *(const bf16x8*)&Gl[tstrip + l16][32 + quad * 8];
    bf16x8 qt0 = *(const bf16x8*)&Qt[tstrip + l16][0  + quad * 8];
    bf16x8 qt1 = *(const bf16x8*)&Qt[tstrip + l16][32 + quad * 8];

    #pragma unroll
    for (int dt = 0; dt < 4; ++dt) {
        bf16x8 x0 = *(const bf16x8*)&Xt[dt * 16 + l16][0  + quad * 8];
        bf16x8 x1 = *(const bf16x8*)&Xt[dt * 16 + l16][32 + quad * 8];
        f32x4 y = {};
        y = __builtin_amdgcn_mfma_f32_16x16x32_bf16(gh0, x0, y, 0, 0, 0);
        y = __builtin_amdgcn_mfma_f32_16x16x32_bf16(gh1, x1, y, 0, 0, 0);
        y = __builtin_amdgcn_mfma_f32_16x16x32_bf16(gl0, x0, y, 0, 0, 0);
        y = __builtin_amdgcn_mfma_f32_16x16x32_bf16(gl1, x1, y, 0, 0, 0);
        f32x4 s4 = {};
        s4 = __builtin_amdgcn_mfma_f32_16x16x32_bf16(qt0, x0, s4, 0, 0, 0);
        s4 = __builtin_amdgcn_mfma_f32_16x16x32_bf16(qt1, x1, s4, 0, 0, 0);
        #pragma unroll
        for (int r = 0; r < 4; ++r) {
            int t = tstrip + quad * 4 + r;       // y row -> separate Y buffer
            yout[(size_t)(b * SEQ + l0 + t) * DINNER + dcol + dt * 16 + l16] = f2bf(y[r]);
            int n = tstrip + quad * 4 + r;       // s row
            Sh[((size_t)((b * NCHUNK + c) * 64 + n)) * 1024 + dcol + dt * 16 + l16] = f2bf(s4[r]);
        }
    }
}

// ---------------------------------------------------------------------------
// Pass B: inter-chunk state scan, in place on Sh (bf16, fp32 carry).
// ---------------------------------------------------------------------------
__global__ __launch_bounds__(256) void state_scan_k(
    u16* __restrict__ Sh, const float* __restrict__ l2a)
{
    int gid = blockIdx.x * 256 + threadIdx.x;    // 262144 total
    int b = gid >> 16, r = gid & 65535, n = r >> 10;
    float a64 = exp2f(64.f * l2a[n]);
    float v = 0.f;
    size_t base = ((size_t)b << 22) + r;
    for (int c = 0; c < NCHUNK; ++c) {
        size_t addr = base + ((size_t)c << 16);
        float s = bf2f(Sh[addr]);
        Sh[addr] = f2bf(v);
        v = fmaf(v, a64, s);
    }
}

// ---------------------------------------------------------------------------
// Pass C: inter-chunk correction, RMW on Y buffer (pitch DINNER).
// Grid (dg=16, c=64, b=4); 256 threads, 4 waves.
// ---------------------------------------------------------------------------
__global__ __launch_bounds__(256) void ssd_inter_k(
    u16* __restrict__ Y, const u16* __restrict__ xBC,
    const u16* __restrict__ Sh, const float* __restrict__ apw,
    const float* __restrict__ l2a)
{
    __shared__ u16 Pl[64][72];       // P[t][n]
    __shared__ u16 Vt[64][72];       // (a*V)[d][n]

    const int dg = blockIdx.x, c = blockIdx.y, b = blockIdx.z;
    const int dcol = dg * 64;
    const int l0 = c * CLEN;
    const int tid = threadIdx.x;
    const int w = tid >> 6, lane = tid & 63;
    const int quad = lane >> 4, l16 = lane & 15;
    const int tstrip = 16 * w;

    // stage P
    {
        const int st_t = tid >> 3, st_n8 = (tid & 7) * 8;
        #pragma unroll
        for (int rep = 0; rep < 2; ++rep) {
            int t = rep * 32 + st_t;
            float Cv[8];
            gload8f(xBC + (size_t)(b * SEQ + l0 + t) * NPROJ + 2112 + st_n8, Cv);
            float4 aw0 = *(const float4*)&apw[t * 64 + st_n8];
            float4 aw1 = *(const float4*)&apw[t * 64 + st_n8 + 4];
            float aw[8] = {aw0.x,aw0.y,aw0.z,aw0.w,aw1.x,aw1.y,aw1.z,aw1.w};
            u16 p8[8];
            #pragma unroll
            for (int j = 0; j < 8; ++j) p8[j] = f2bf(Cv[j] * aw[j]);
            *(bf16x8*)&Pl[t][st_n8] = *(bf16x8*)p8;
        }
    }
    // stage aV transposed (bf16 Sh read, vector 16B)
    {
        #pragma unroll
        for (int rep = 0; rep < 2; ++rep) {
            int idx = rep * 256 + tid;          // 0..511
            int vn = idx >> 3, vd8 = (idx & 7) * 8;
            float an = exp2f(l2a[vn]);
            bf16x8 vv = *(const bf16x8*)&Sh[((size_t)((b * NCHUNK + c) * 64 + vn)) * 1024 + dcol + vd8];
            #pragma unroll
            for (int j = 0; j < 8; ++j) Vt[vd8 + j][vn] = f2bf(an * bf2f((u16)vv[j]));
        }
    }
    __syncthreads();

    bf16x8 af0 = *(const bf16x8*)&Pl[tstrip + l16][0  + quad * 8];
    bf16x8 af1 = *(const bf16x8*)&Pl[tstrip + l16][32 + quad * 8];
    #pragma unroll
    for (int dt = 0; dt < 4; ++dt) {
        bf16x8 hb0 = *(const bf16x8*)&Vt[dt * 16 + l16][0  + quad * 8];
        bf16x8 hb1 = *(const bf16x8*)&Vt[dt * 16 + l16][32 + quad * 8];
        f32x4 y = {};
        y = __builtin_amdgcn_mfma_f32_16x16x32_bf16(af0, hb0, y, 0, 0, 0);
        y = __builtin_amdgcn_mfma_f32_16x16x32_bf16(af1, hb1, y, 0, 0, 0);
        #pragma unroll
        for (int r = 0; r < 4; ++r) {
            int t = tstrip + quad * 4 + r;
            size_t addr = (size_t)(b * SEQ + l0 + t) * DINNER + dcol + dt * 16 + l16;
            Y[addr] = f2bf(bf2f(Y[addr]) + y[r]);
        }
    }
}

// ---------------------------------------------------------------------------
// Gate (y * silu(z)) + LayerNorm over 1024 channels.  One block per row.
// ---------------------------------------------------------------------------
__global__ __launch_bounds__(256) void gate_k(
    const u16* __restrict__ Y, const u16* __restrict__ xBC,
    const float* __restrict__ ln_w, const float* __restrict__ ln_b,
    u16* __restrict__ yn)
{
    __shared__ float r1[4], r2[4];
    const int row = blockIdx.x;
    const int tid = threadIdx.x;
    const int lane = tid & 63, wid = tid >> 6;

    float gv[4];
    {
        const ushort4 yv = *(const ushort4*)(Y + (size_t)row * DINNER + tid * 4);
        const ushort4 zv = *(const ushort4*)(xBC + (size_t)row * NPROJ + 1024 + tid * 4);
        gv[0] = bf2f(yv.x) * silu_f(bf2f(zv.x));
        gv[1] = bf2f(yv.y) * silu_f(bf2f(zv.y));
        gv[2] = bf2f(yv.z) * silu_f(bf2f(zv.z));
        gv[3] = bf2f(yv.w) * silu_f(bf2f(zv.w));
    }
    float ps = gv[0] + gv[1] + gv[2] + gv[3];
    float pq = gv[0]*gv[0] + gv[1]*gv[1] + gv[2]*gv[2] + gv[3]*gv[3];
    #pragma unroll
    for (int off = 1; off < 64; off <<= 1) {
        ps += __shfl_xor(ps, off);
        pq += __shfl_xor(pq, off);
    }
    if (lane == 0) { r1[wid] = ps; r2[wid] = pq; }
    __syncthreads();
    float ts = r1[0] + r1[1] + r1[2] + r1[3];
    float tq = r2[0] + r2[1] + r2[2] + r2[3];
    float mu = ts * (1.0f / DINNER);
    float var = tq * (1.0f / DINNER) - mu * mu;
    float inv = rsqrtf(var + 1e-5f);

    u16 outv[4];
    #pragma unroll
    for (int j = 0; j < 4; ++j) {
        int c = tid * 4 + j;
        float v = (gv[j] - mu) * inv * ln_w[c] + ln_b[c];
        outv[j] = f2bf(v);
    }
    *(ushort4*)(yn + (size_t)row * DINNER + tid * 4) = *(ushort4*)outv;
}

// ---------------------------------------------------------------------------
extern "C" void kernel_launch(void* const* d_in, const int* in_sizes, int n_in,
                              void* d_out, int out_size, void* d_ws, size_t ws_size,
                              hipStream_t stream) {
    const float* x   = (const float*)d_in[0];
    const float* w1  = (const float*)d_in[1];
    const float* cw  = (const float*)d_in[2];
    const float* cb  = (const float*)d_in[3];
    const float* ap  = (const float*)d_in[4];
    const float* lnw = (const float*)d_in[5];
    const float* lnb = (const float*)d_in[6];
    const float* w2  = (const float*)d_in[7];
    float* out = (float*)d_out;

    // ws layout (~107 MiB):
    u16* xBC   = (u16*)d_ws;                             // MROWS x 2176
    u16* xact  = xBC + (size_t)MROWS * NPROJ;            // MROWS x 1024
    u16* x_bf  = xact;                                   // gemm1 A; dead after gemm1,
                                                         // then reused as Y buffer
    u16* w2_bf = xact + (size_t)MROWS * DINNER;          // 1024x1024
    float* l2a  = (float*)(w2_bf + (size_t)DMODEL * DINNER);  // 64
    float* apw  = l2a + 64;                              // 64x64
    float* ainv = apw + 4096;                            // 64x64
    // w1p (padded weights, 4.7MB) then Sh (bf16 S/V, 33.5MB) park in d_out:
    // w1p dead after gemm1; Sh written by pass A, consumed by ssd_inter
    // before gemm2 overwrites d_out with the final output.
    u16* w1p = (u16*)d_out;                              // 2304x1024 bf16
    u16* Sh  = (u16*)d_out;                              // 4 x 64 x 64 x 1024 bf16

    cast_f2b<<<(MROWS * DMODEL / 8) / 256, 256, 0, stream>>>(x, x_bf, MROWS * DMODEL / 8);
    cast_w1p_k<<<(NPAD * DMODEL / 8) / 256, 256, 0, stream>>>(w1, w1p);
    cast_f2b<<<(DMODEL * DINNER / 8) / 256, 256, 0, stream>>>(w2, w2_bf, DMODEL * DINNER / 8);
    tables_k<<<1, 256, 0, stream>>>(ap, l2a, apw, ainv);

    gemm8p_k<u16, 9, NPROJ, NPROJ><<<9 * 64, 512, 0, stream>>>(x_bf, w1p, xBC);

    // conv fused into intra X-staging; Y -> xact (x_bf dead after gemm1)
    ssd_intra_k<<<dim3(16, NCHUNK, BATCH), 256, 0, stream>>>(cw, cb, xBC, xact, Sh, apw, ainv);
    state_scan_k<<<1024, 256, 0, stream>>>(Sh, l2a);
    ssd_inter_k<<<dim3(16, NCHUNK, BATCH), 256, 0, stream>>>(xact, xBC, Sh, apw, l2a);

    gate_k<<<MROWS, 256, 0, stream>>>(xact, xBC, lnw, lnb, xact);
    gemm8p_k<float, 4, DMODEL, DMODEL><<<4 * 64, 512, 0, stream>>>(xact, w2_bf, out);
}

// Round 13
// 365.951 us; speedup vs baseline: 3.5529x; 1.0537x over previous
//
#include <hip/hip_runtime.h>

typedef unsigned short u16;
typedef unsigned int u32;
typedef __attribute__((ext_vector_type(8))) short bf16x8;
typedef __attribute__((ext_vector_type(4))) float f32x4;

#define BATCH 4
#define SEQ 4096
#define DMODEL 1024
#define DINNER 1024
#define NPROJ 2176          // 2*DINNER + 2*DSTATE = 2048 + 128
#define MROWS (BATCH*SEQ)   // 16384
#define NCHUNK 64           // chunks per sequence
#define CLEN 64             // chunk length

__device__ __forceinline__ float bf2f(u16 u) {
    union { u32 i; float f; } v; v.i = ((u32)u) << 16; return v.f;
}
__device__ __forceinline__ u16 f2bf(float f) {
    union { float f; u32 i; } v; v.f = f;
    u32 r = v.i + 0x7FFFu + ((v.i >> 16) & 1u);
    return (u16)(r >> 16);
}
__device__ __forceinline__ float silu_f(float x) { return x / (1.0f + expf(-x)); }

__device__ __forceinline__ void gload8f(const u16* p, float* o) {
    bf16x8 v = *(const bf16x8*)p;
    #pragma unroll
    for (int j = 0; j < 8; ++j) o[j] = bf2f((u16)v[j]);
}

// async global->LDS, 16B per lane; LDS dest = wave-uniform base + lane*16
__device__ __forceinline__ void ld_lds16(const u16* g, u16* l) {
    __builtin_amdgcn_global_load_lds(
        (const __attribute__((address_space(1))) u32*)g,
        (__attribute__((address_space(3))) u32*)l, 16, 0, 0);
}

// ---------------------------------------------------------------------------
// fp32 -> bf16 cast, 8 elems/thread
// ---------------------------------------------------------------------------
__global__ __launch_bounds__(256) void cast_f2b(
    const float* __restrict__ src, u16* __restrict__ dst, int n8)
{
    int i = blockIdx.x * 256 + threadIdx.x;
    if (i >= n8) return;
    size_t o = (size_t)i * 8;
    float4 a = *(const float4*)(src + o);
    float4 b = *(const float4*)(src + o + 4);
    u16 v[8] = {f2bf(a.x), f2bf(a.y), f2bf(a.z), f2bf(a.w),
                f2bf(b.x), f2bf(b.y), f2bf(b.z), f2bf(b.w)};
    *(bf16x8*)(dst + o) = *(bf16x8*)v;
}

// ---------------------------------------------------------------------------
// Decay tables: l2a[n] = log2(a[n]); apw[t][n] = a[n]^t; ainv[t][n] = a[n]^-t
// ---------------------------------------------------------------------------
__global__ __launch_bounds__(256) void tables_k(
    const float* __restrict__ A_param, float* __restrict__ l2a_g,
    float* __restrict__ apw, float* __restrict__ ainv)
{
    __shared__ float l2s[64];
    int tid = threadIdx.x;
    if (tid < 64) {
        float v = -expf(A_param[tid]) * 1.44269504088896340736f;
        l2s[tid] = v;
        l2a_g[tid] = v;
    }
    __syncthreads();
    #pragma unroll
    for (int i = 0; i < 16; ++i) {
        int e = tid * 16 + i;          // e = t*64 + n
        int t = e >> 6, n = e & 63;
        float x = (float)t * l2s[n];
        apw[e]  = exp2f(x);
        ainv[e] = exp2f(-x);
    }
}

// ---------------------------------------------------------------------------
// 8-phase 256x256 NT GEMM (HK-style schedule in plain HIP).
// Race-free uniform-vmcnt calendar (round-3) — kernel body UNCHANGED.
// gemm1 main now uses GN=8 (N=2048, grid 512 = exactly 2 rounds); the
// 128-col remainder is handled by gemm_rem_k below.
// ---------------------------------------------------------------------------
#define GK 1024
#define GNT 16   // K tiles of 64

template<typename TO, int GN, int NV, int LDC>
__global__ __launch_bounds__(512, 1) void gemm8p_k(
    const u16* __restrict__ A, const u16* __restrict__ B, TO* __restrict__ C)
{
    __shared__ u16 lds[65536];   // 128 KiB: A[2buf][2half][128*64] then B same

    const int cpx = (GN * 64) >> 3;
    const int bid = blockIdx.x;
    const int swz = (bid & 7) * cpx + (bid >> 3);   // XCD swizzle (nwg%8==0)
    const int bm = swz / GN, bn = swz % GN;
    const int m0 = bm * 256, n0 = bn * 256;

    const int tid = threadIdx.x;
    const int wid = tid >> 6, lane = tid & 63;
    const int wm = wid >> 2, wn = wid & 3;
    const int quad = lane >> 4, l16 = lane & 15;
    const int xsw = (l16 & 7) << 3;                 // read-side XOR (u16 units)

    u16* L = lds;
    const u16* Ab = A + (size_t)m0 * GK;
    const u16* Bb = B + (size_t)n0 * GK;

    auto stage = [&](const u16* gbase, u16* ldsb) {
        {
            int c = tid;
            int row = c >> 3, slot = (c & 7) ^ (row & 7);
            ld_lds16(gbase + (size_t)row * GK + slot * 8,
                     ldsb + ((tid & ~63) << 3));
        }
        {
            int c = 512 + tid;
            int row = c >> 3, slot = (c & 7) ^ (row & 7);
            ld_lds16(gbase + (size_t)row * GK + slot * 8,
                     ldsb + ((512 + (tid & ~63)) << 3));
        }
    };
    auto rdfrag = [&](const u16* base, int rh, int kh) -> bf16x8 {
        return *(const bf16x8*)(base + rh * 64 + ((kh * 32 + quad * 8) ^ xsw));
    };

    bf16x8 aLo[4][2], aHi[4][2], bLo[2][2], bHi[2][2];
    f32x4 acc[8][4] = {};

    // ---- prologue: tile0 fully + both A halves of tile1 in flight
    stage(Ab,                     L);               // A0 t0
    stage(Ab + 128 * GK,          L + 8192);        // A1 t0
    stage(Bb,                     L + 32768);       // B0 t0
    stage(Bb + 128 * GK,          L + 40960);       // B1 t0
    stage(Ab + 64,                L + 16384);       // A0 t1 -> buf1
    stage(Ab + 128 * GK + 64,     L + 24576);       // A1 t1 -> buf1
    asm volatile("s_waitcnt vmcnt(4)" ::: "memory");   // tile0 landed
    __builtin_amdgcn_s_barrier();
    {
        const u16* Ard = L + wm * 8192;
        #pragma unroll
        for (int i = 0; i < 4; ++i)
            #pragma unroll
            for (int kh = 0; kh < 2; ++kh)
                aLo[i][kh] = rdfrag(Ard, i * 16 + l16, kh);
    }

    for (int t = 0; t < GNT; ++t) {
        const int cb = t & 1;
        u16* Acur = L + cb * 16384;
        u16* Anxt = L + (cb ^ 1) * 16384;
        u16* Bnxt = L + 32768 + (cb ^ 1) * 16384;
        const u16* ArdC = Acur + wm * 8192;
        const u16* ArdN = Anxt + wm * 8192;
        const u16* BrdC = L + 32768 + cb * 16384 + (wn >> 1) * 8192;
        const int brh = (wn & 1) * 64;

        // ---------------- q0: MFMA quadrant (lo, lo) ----------------
        #pragma unroll
        for (int j = 0; j < 2; ++j)
            #pragma unroll
            for (int kh = 0; kh < 2; ++kh)
                bLo[j][kh] = rdfrag(BrdC, brh + j * 16 + l16, kh);
        if (t + 1 < GNT) stage(Bb + (t + 1) * 64, Bnxt);            // B0(t+1)
        __builtin_amdgcn_s_barrier();
        asm volatile("s_waitcnt lgkmcnt(0)" ::: "memory");
        __builtin_amdgcn_s_setprio(1);
        #pragma unroll
        for (int kh = 0; kh < 2; ++kh)
            #pragma unroll
            for (int i = 0; i < 4; ++i)
                #pragma unroll
                for (int j = 0; j < 2; ++j)
                    acc[i][j] = __builtin_amdgcn_mfma_f32_16x16x32_bf16(
                        aLo[i][kh], bLo[j][kh], acc[i][j], 0, 0, 0);
        __builtin_amdgcn_s_setprio(0);
        __builtin_amdgcn_s_barrier();

        // ---------------- q1: (lo, hi) ----------------
        #pragma unroll
        for (int j = 0; j < 2; ++j)
            #pragma unroll
            for (int kh = 0; kh < 2; ++kh)
                bHi[j][kh] = rdfrag(BrdC, brh + 32 + j * 16 + l16, kh);
        if (t + 1 < GNT) stage(Bb + 128 * GK + (t + 1) * 64, Bnxt + 8192); // B1(t+1)
        __builtin_amdgcn_s_barrier();
        asm volatile("s_waitcnt lgkmcnt(0)" ::: "memory");
        __builtin_amdgcn_s_setprio(1);
        #pragma unroll
        for (int kh = 0; kh < 2; ++kh)
            #pragma unroll
            for (int i = 0; i < 4; ++i)
                #pragma unroll
                for (int j = 0; j < 2; ++j)
                    acc[i][2 + j] = __builtin_amdgcn_mfma_f32_16x16x32_bf16(
                        aLo[i][kh], bHi[j][kh], acc[i][2 + j], 0, 0, 0);
        __builtin_amdgcn_s_setprio(0);
        __builtin_amdgcn_s_barrier();

        // ---------------- q2: (hi, hi) ----------------
        #pragma unroll
        for (int i = 0; i < 4; ++i)
            #pragma unroll
            for (int kh = 0; kh < 2; ++kh)
                aHi[i][kh] = rdfrag(ArdC, 64 + i * 16 + l16, kh);
        if (t + 2 < GNT) stage(Ab + (t + 2) * 64, Acur);            // A0(t+2)
        if (t + 2 < GNT)      { asm volatile("s_waitcnt vmcnt(6)" ::: "memory"); }
        else if (t + 1 < GNT) { asm volatile("s_waitcnt vmcnt(4)" ::: "memory"); }
        __builtin_amdgcn_s_barrier();
        asm volatile("s_waitcnt lgkmcnt(0)" ::: "memory");
        __builtin_amdgcn_s_setprio(1);
        #pragma unroll
        for (int kh = 0; kh < 2; ++kh)
            #pragma unroll
            for (int i = 0; i < 4; ++i)
                #pragma unroll
                for (int j = 0; j < 2; ++j)
                    acc[4 + i][2 + j] = __builtin_amdgcn_mfma_f32_16x16x32_bf16(
                        aHi[i][kh], bHi[j][kh], acc[4 + i][2 + j], 0, 0, 0);
        __builtin_amdgcn_s_setprio(0);
        __builtin_amdgcn_s_barrier();

        // ---------------- q3: (hi, lo); prefetch next aLo ----------------
        if (t + 1 < GNT) {
            #pragma unroll
            for (int i = 0; i < 4; ++i)
                #pragma unroll
                for (int kh = 0; kh < 2; ++kh)
                    aLo[i][kh] = rdfrag(ArdN, i * 16 + l16, kh);
        }
        if (t + 2 < GNT) stage(Ab + 128 * GK + (t + 2) * 64, Acur + 8192); // A1(t+2)
        if (t + 2 < GNT)      { asm volatile("s_waitcnt vmcnt(4)" ::: "memory"); }
        else if (t + 1 < GNT) { asm volatile("s_waitcnt vmcnt(0)" ::: "memory"); }
        __builtin_amdgcn_s_barrier();
        asm volatile("s_waitcnt lgkmcnt(0)" ::: "memory");
        __builtin_amdgcn_s_setprio(1);
        #pragma unroll
        for (int kh = 0; kh < 2; ++kh)
            #pragma unroll
            for (int i = 0; i < 4; ++i)
                #pragma unroll
                for (int j = 0; j < 2; ++j)
                    acc[4 + i][j] = __builtin_amdgcn_mfma_f32_16x16x32_bf16(
                        aHi[i][kh], bLo[j][kh], acc[4 + i][j], 0, 0, 0);
        __builtin_amdgcn_s_setprio(0);
        __builtin_amdgcn_s_barrier();
    }

    // ---- epilogue: LDS transpose -> coalesced stores ----
    __syncthreads();
    if constexpr (sizeof(TO) == 2) {
        u16* eld = lds;          // viewed as [256][256] bf16
        #pragma unroll
        for (int i = 0; i < 8; ++i)
            #pragma unroll
            for (int j = 0; j < 4; ++j)
                #pragma unroll
                for (int r = 0; r < 4; ++r)
                    eld[(size_t)(wm * 128 + i * 16 + quad * 4 + r) * 256 +
                        wn * 64 + j * 16 + l16] = f2bf(acc[i][j][r]);
        __syncthreads();
        #pragma unroll
        for (int rep = 0; rep < 16; ++rep) {
            int cc = rep * 512 + tid;
            int row = cc >> 5, c8 = (cc & 31) * 8;
            if (n0 + c8 < NV)
                *(bf16x8*)(C + (size_t)(m0 + row) * LDC + n0 + c8) =
                    *(const bf16x8*)(eld + (size_t)row * 256 + c8);
        }
    } else {
        float* eldf = (float*)lds;   // [128][256] fp32, two passes
        #pragma unroll
        for (int h = 0; h < 2; ++h) {
            if (wm == h) {
                #pragma unroll
                for (int i = 0; i < 8; ++i)
                    #pragma unroll
                    for (int j = 0; j < 4; ++j)
                        #pragma unroll
                        for (int r = 0; r < 4; ++r)
                            eldf[(size_t)(i * 16 + quad * 4 + r) * 256 +
                                 wn * 64 + j * 16 + l16] = acc[i][j][r];
            }
            __syncthreads();
            #pragma unroll
            for (int rep = 0; rep < 16; ++rep) {
                int cc = rep * 512 + tid;
                int row = cc >> 6, c4 = (cc & 63) * 4;
                *(float4*)(C + (size_t)(m0 + h * 128 + row) * LDC + n0 + c4) =
                    *(const float4*)(eldf + (size_t)row * 256 + c4);
            }
            __syncthreads();
        }
    }
}

// ---------------------------------------------------------------------------
// gemm1 remainder: C[:, 2048:2176) = A @ B2^T, B2 = w1_bf rows 2048..2175.
// 64M x 128N tiles, BK=64, 512 threads (8 waves: wave w -> M-strip (w&3)*16,
// N-half (w>>2)*64).  Single-buffered 24 KB LDS, plain __syncthreads loop
// (no manual vmcnt calendar).  Grid 256 = 1 round.  Accumulation order
// (k0 asc, kh inner) matches gemm8p -> bit-identical output.
// ---------------------------------------------------------------------------
__global__ __launch_bounds__(512) void gemm_rem_k(
    const u16* __restrict__ A, const u16* __restrict__ B2, u16* __restrict__ C)
{
    __shared__ u16 As[64 * 64];      // 8 KB
    __shared__ u16 Bs[128 * 64];     // 16 KB

    const int bid = blockIdx.x;                  // 256 = 8*32
    const int swz = (bid & 7) * 32 + (bid >> 3);
    const int m0 = swz * 64;
    const int tid = threadIdx.x;
    const int wid = tid >> 6, lane = tid & 63;
    const int quad = lane >> 4, l16 = lane & 15;
    const int xsw = (l16 & 7) << 3;
    const int ar = (wid & 3) * 16;               // wave's A-row strip
    const int bn = (wid >> 2) * 64;              // wave's N-half (B2 row base)

    f32x4 acc[4] = {};

    for (int k0 = 0; k0 < GK; k0 += 64) {
        // stage A 64x64 (512 chunks, 1/thread) + B2 128x64 (1024 chunks, 2/thread)
        {
            int row = tid >> 3, slot = (tid & 7) ^ (row & 7);
            ld_lds16(A + (size_t)(m0 + row) * GK + k0 + slot * 8,
                     &As[(tid & ~63) << 3]);
        }
        #pragma unroll
        for (int it = 0; it < 2; ++it) {
            int c = it * 512 + tid;
            int row = c >> 3, slot = (c & 7) ^ (row & 7);
            ld_lds16(B2 + (size_t)row * GK + k0 + slot * 8,
                     &Bs[(it * 512 + (tid & ~63)) << 3]);
        }
        __syncthreads();   // drains vmcnt (compiler-inserted) + barrier

        bf16x8 a0 = *(const bf16x8*)&As[(ar + l16) * 64 + ((quad * 8) ^ xsw)];
        bf16x8 a1 = *(const bf16x8*)&As[(ar + l16) * 64 + ((32 + quad * 8) ^ xsw)];
        #pragma unroll
        for (int j = 0; j < 4; ++j) {
            bf16x8 b0 = *(const bf16x8*)&Bs[(bn + j * 16 + l16) * 64 + ((quad * 8) ^ xsw)];
            bf16x8 b1 = *(const bf16x8*)&Bs[(bn + j * 16 + l16) * 64 + ((32 + quad * 8) ^ xsw)];
            acc[j] = __builtin_amdgcn_mfma_f32_16x16x32_bf16(a0, b0, acc[j], 0, 0, 0);
            acc[j] = __builtin_amdgcn_mfma_f32_16x16x32_bf16(a1, b1, acc[j], 0, 0, 0);
        }
        __syncthreads();   // all reads done before next stage overwrites
    }

    // epilogue: transpose via Bs (exactly 16 KB = [64][128] u16), vector stores
    u16* eld = Bs;
    #pragma unroll
    for (int j = 0; j < 4; ++j)
        #pragma unroll
        for (int r = 0; r < 4; ++r)
            eld[(ar + quad * 4 + r) * 128 + bn + j * 16 + l16] = f2bf(acc[j][r]);
    __syncthreads();
    #pragma unroll
    for (int rep = 0; rep < 2; ++rep) {
        int c = rep * 512 + tid;                 // 1024 chunks of 8 u16
        int row = c >> 4, c8 = (c & 15) * 8;
        *(bf16x8*)(C + (size_t)(m0 + row) * NPROJ + 2048 + c8) =
            *(const bf16x8*)(eld + row * 128 + c8);
    }
}

// ---------------------------------------------------------------------------
// Pass A: intra-chunk SSD with fused causal conv (K=4) + bias + SiLU on the
// X-staging path.  Y -> separate yout buffer (xBC x-cols stay read-only).
// Grid (dg=16, c=64, b=4); 256 threads, 4 waves.  S output bf16.
// ---------------------------------------------------------------------------
__global__ __launch_bounds__(256) void ssd_intra_k(
    const float* __restrict__ conv_w, const float* __restrict__ conv_b,
    const u16* __restrict__ xBC, u16* __restrict__ yout,
    u16* __restrict__ Sh, const float* __restrict__ apw,
    const float* __restrict__ ainv)
{
    __shared__ u16 Pl[64][72];       // P[t][n] = C_t a^t
    __shared__ u16 Ql[64][72];       // Q[s][n] = B_s a^-s, then Ghi[t][s]
    __shared__ u16 Gl[64][72];       // Glo[t][s]
    __shared__ u16 Qt[64][72];       // Qt[n][s] = B_s a^{63-s}
    __shared__ u16 Xt[64][72];       // X^T [d][s]  (conv+silu applied)

    const int dg = blockIdx.x, c = blockIdx.y, b = blockIdx.z;
    const int dcol = dg * 64;
    const int l0 = c * CLEN;
    const int tid = threadIdx.x;
    const int w = tid >> 6, lane = tid & 63;
    const int quad = lane >> 4, l16 = lane & 15;
    const int tstrip = 16 * w;

    // stage B/C -> P, Q, Qt
    {
        const int st_t = tid >> 3, st_n8 = (tid & 7) * 8;
        #pragma unroll
        for (int rep = 0; rep < 2; ++rep) {
            int t = rep * 32 + st_t;
            size_t row = (size_t)(b * SEQ + l0 + t) * NPROJ;
            float Bv[8], Cv[8];
            gload8f(xBC + row + 2048 + st_n8, Bv);
            gload8f(xBC + row + 2112 + st_n8, Cv);
            float4 aw0 = *(const float4*)&apw[t * 64 + st_n8];
            float4 aw1 = *(const float4*)&apw[t * 64 + st_n8 + 4];
            float4 ai0 = *(const float4*)&ainv[t * 64 + st_n8];
            float4 ai1 = *(const float4*)&ainv[t * 64 + st_n8 + 4];
            float4 ar0 = *(const float4*)&apw[(63 - t) * 64 + st_n8];
            float4 ar1 = *(const float4*)&apw[(63 - t) * 64 + st_n8 + 4];
            float aw[8] = {aw0.x,aw0.y,aw0.z,aw0.w,aw1.x,aw1.y,aw1.z,aw1.w};
            float ai[8] = {ai0.x,ai0.y,ai0.z,ai0.w,ai1.x,ai1.y,ai1.z,ai1.w};
            float ar[8] = {ar0.x,ar0.y,ar0.z,ar0.w,ar1.x,ar1.y,ar1.z,ar1.w};
            u16 p8[8], q8[8];
            #pragma unroll
            for (int j = 0; j < 8; ++j) {
                p8[j] = f2bf(Cv[j] * aw[j]);
                q8[j] = f2bf(Bv[j] * ai[j]);
            }
            *(bf16x8*)&Pl[t][st_n8] = *(bf16x8*)p8;
            *(bf16x8*)&Ql[t][st_n8] = *(bf16x8*)q8;
            #pragma unroll
            for (int j = 0; j < 8; ++j)
                Qt[st_n8 + j][t] = f2bf(Bv[j] * ar[j]);
        }
    }
    // stage X transposed, computing conv+bias+SiLU on the fly from xBC x-cols
    {
        const int xt_d8 = (tid & 7) * 8;         // same channels both reps
        const int ch0 = dcol + xt_d8;
        float4 wv[8];
        #pragma unroll
        for (int j = 0; j < 8; ++j)
            wv[j] = *(const float4*)(conv_w + (ch0 + j) * 4);
        float bias[8];
        {
            float4 b0 = *(const float4*)(conv_b + ch0);
            float4 b1 = *(const float4*)(conv_b + ch0 + 4);
            bias[0]=b0.x; bias[1]=b0.y; bias[2]=b0.z; bias[3]=b0.w;
            bias[4]=b1.x; bias[5]=b1.y; bias[6]=b1.z; bias[7]=b1.w;
        }
        #pragma unroll
        for (int rep = 0; rep < 2; ++rep) {
            int xt_t = (tid >> 3) + rep * 32;    // 0..63
            float acc[8];
            #pragma unroll
            for (int j = 0; j < 8; ++j) acc[j] = bias[j];
            #pragma unroll
            for (int k = 0; k < 4; ++k) {
                int lt = l0 + xt_t - 3 + k;      // within-sequence index
                if (lt < 0) continue;
                float v[8];
                gload8f(xBC + (size_t)(b * SEQ + lt) * NPROJ + ch0, v);
                #pragma unroll
                for (int j = 0; j < 8; ++j) {
                    const float* wj = (const float*)&wv[j];
                    acc[j] += v[j] * wj[k];
                }
            }
            #pragma unroll
            for (int j = 0; j < 8; ++j)
                Xt[xt_d8 + j][xt_t] = f2bf(silu_f(acc[j]));
        }
    }
    __syncthreads();

    // ---- G = P Q^T (per wave: 16-t strip) ----
    bf16x8 af0 = *(const bf16x8*)&Pl[tstrip + l16][0  + quad * 8];
    bf16x8 af1 = *(const bf16x8*)&Pl[tstrip + l16][32 + quad * 8];
    f32x4 g[4] = {};
    #pragma unroll
    for (int j4 = 0; j4 < 4; ++j4) {
        bf16x8 b0 = *(const bf16x8*)&Ql[j4 * 16 + l16][0  + quad * 8];
        bf16x8 b1 = *(const bf16x8*)&Ql[j4 * 16 + l16][32 + quad * 8];
        g[j4] = __builtin_amdgcn_mfma_f32_16x16x32_bf16(af0, b0, g[j4], 0, 0, 0);
        g[j4] = __builtin_amdgcn_mfma_f32_16x16x32_bf16(af1, b1, g[j4], 0, 0, 0);
    }
    __syncthreads();

    // ---- mask (s<=t) + hi/lo split: Ghi->Ql, Glo->Gl ----
    #pragma unroll
    for (int j4 = 0; j4 < 4; ++j4) {
        #pragma unroll
        for (int r = 0; r < 4; ++r) {
            int t = tstrip + quad * 4 + r;
            int s = j4 * 16 + l16;
            float val = (s <= t) ? g[j4][r] : 0.f;
            u16 hi = f2bf(val);
            Ql[t][s] = hi;
            Gl[t][s] = f2bf(val - bf2f(hi));
        }
    }
    __syncthreads();

    // ---- Y strip [16t x 64d] and S strip [16n x 64d] ----
    bf16x8 gh0 = *(const bf16x8*)&Ql[tstrip + l16][0  + quad * 8];
    bf16x8 gh1 = *(const bf16x8*)&Ql[tstrip + l16][32 + quad * 8];
    bf16x8 gl0 = *(const bf16x8*)&Gl[tstrip + l16][0  + quad * 8];
    bf16x8 gl1 = *(const bf16x8*)&Gl[tstrip + l16][32 + quad * 8];
    bf16x8 qt0 = *(const bf16x8*)&Qt[tstrip + l16][0  + quad * 8];
    bf16x8 qt1 = *(const bf16x8*)&Qt[tstrip + l16][32 + quad * 8];

    #pragma unroll
    for (int dt = 0; dt < 4; ++dt) {
        bf16x8 x0 = *(const bf16x8*)&Xt[dt * 16 + l16][0  + quad * 8];
        bf16x8 x1 = *(const bf16x8*)&Xt[dt * 16 + l16][32 + quad * 8];
        f32x4 y = {};
        y = __builtin_amdgcn_mfma_f32_16x16x32_bf16(gh0, x0, y, 0, 0, 0);
        y = __builtin_amdgcn_mfma_f32_16x16x32_bf16(gh1, x1, y, 0, 0, 0);
        y = __builtin_amdgcn_mfma_f32_16x16x32_bf16(gl0, x0, y, 0, 0, 0);
        y = __builtin_amdgcn_mfma_f32_16x16x32_bf16(gl1, x1, y, 0, 0, 0);
        f32x4 s4 = {};
        s4 = __builtin_amdgcn_mfma_f32_16x16x32_bf16(qt0, x0, s4, 0, 0, 0);
        s4 = __builtin_amdgcn_mfma_f32_16x16x32_bf16(qt1, x1, s4, 0, 0, 0);
        #pragma unroll
        for (int r = 0; r < 4; ++r) {
            int t = tstrip + quad * 4 + r;       // y row -> separate Y buffer
            yout[(size_t)(b * SEQ + l0 + t) * DINNER + dcol + dt * 16 + l16] = f2bf(y[r]);
            int n = tstrip + quad * 4 + r;       // s row
            Sh[((size_t)((b * NCHUNK + c) * 64 + n)) * 1024 + dcol + dt * 16 + l16] = f2bf(s4[r]);
        }
    }
}

// ---------------------------------------------------------------------------
// Pass B: inter-chunk state scan, in place on Sh (bf16, fp32 carry).
// ---------------------------------------------------------------------------
__global__ __launch_bounds__(256) void state_scan_k(
    u16* __restrict__ Sh, const float* __restrict__ l2a)
{
    int gid = blockIdx.x * 256 + threadIdx.x;    // 262144 total
    int b = gid >> 16, r = gid & 65535, n = r >> 10;
    float a64 = exp2f(64.f * l2a[n]);
    float v = 0.f;
    size_t base = ((size_t)b << 22) + r;
    for (int c = 0; c < NCHUNK; ++c) {
        size_t addr = base + ((size_t)c << 16);
        float s = bf2f(Sh[addr]);
        Sh[addr] = f2bf(v);
        v = fmaf(v, a64, s);
    }
}

// ---------------------------------------------------------------------------
// Pass C: inter-chunk correction, RMW on Y buffer (pitch DINNER).
// Grid (dg=16, c=64, b=4); 256 threads, 4 waves.
// ---------------------------------------------------------------------------
__global__ __launch_bounds__(256) void ssd_inter_k(
    u16* __restrict__ Y, const u16* __restrict__ xBC,
    const u16* __restrict__ Sh, const float* __restrict__ apw,
    const float* __restrict__ l2a)
{
    __shared__ u16 Pl[64][72];       // P[t][n]
    __shared__ u16 Vt[64][72];       // (a*V)[d][n]

    const int dg = blockIdx.x, c = blockIdx.y, b = blockIdx.z;
    const int dcol = dg * 64;
    const int l0 = c * CLEN;
    const int tid = threadIdx.x;
    const int w = tid >> 6, lane = tid & 63;
    const int quad = lane >> 4, l16 = lane & 15;
    const int tstrip = 16 * w;

    // stage P
    {
        const int st_t = tid >> 3, st_n8 = (tid & 7) * 8;
        #pragma unroll
        for (int rep = 0; rep < 2; ++rep) {
            int t = rep * 32 + st_t;
            float Cv[8];
            gload8f(xBC + (size_t)(b * SEQ + l0 + t) * NPROJ + 2112 + st_n8, Cv);
            float4 aw0 = *(const float4*)&apw[t * 64 + st_n8];
            float4 aw1 = *(const float4*)&apw[t * 64 + st_n8 + 4];
            float aw[8] = {aw0.x,aw0.y,aw0.z,aw0.w,aw1.x,aw1.y,aw1.z,aw1.w};
            u16 p8[8];
            #pragma unroll
            for (int j = 0; j < 8; ++j) p8[j] = f2bf(Cv[j] * aw[j]);
            *(bf16x8*)&Pl[t][st_n8] = *(bf16x8*)p8;
        }
    }
    // stage aV transposed (bf16 Sh read, vector 16B)
    {
        #pragma unroll
        for (int rep = 0; rep < 2; ++rep) {
            int idx = rep * 256 + tid;          // 0..511
            int vn = idx >> 3, vd8 = (idx & 7) * 8;
            float an = exp2f(l2a[vn]);
            bf16x8 vv = *(const bf16x8*)&Sh[((size_t)((b * NCHUNK + c) * 64 + vn)) * 1024 + dcol + vd8];
            #pragma unroll
            for (int j = 0; j < 8; ++j) Vt[vd8 + j][vn] = f2bf(an * bf2f((u16)vv[j]));
        }
    }
    __syncthreads();

    bf16x8 af0 = *(const bf16x8*)&Pl[tstrip + l16][0  + quad * 8];
    bf16x8 af1 = *(const bf16x8*)&Pl[tstrip + l16][32 + quad * 8];
    #pragma unroll
    for (int dt = 0; dt < 4; ++dt) {
        bf16x8 hb0 = *(const bf16x8*)&Vt[dt * 16 + l16][0  + quad * 8];
        bf16x8 hb1 = *(const bf16x8*)&Vt[dt * 16 + l16][32 + quad * 8];
        f32x4 y = {};
        y = __builtin_amdgcn_mfma_f32_16x16x32_bf16(af0, hb0, y, 0, 0, 0);
        y = __builtin_amdgcn_mfma_f32_16x16x32_bf16(af1, hb1, y, 0, 0, 0);
        #pragma unroll
        for (int r = 0; r < 4; ++r) {
            int t = tstrip + quad * 4 + r;
            size_t addr = (size_t)(b * SEQ + l0 + t) * DINNER + dcol + dt * 16 + l16;
            Y[addr] = f2bf(bf2f(Y[addr]) + y[r]);
        }
    }
}

// ---------------------------------------------------------------------------
// Gate (y * silu(z)) + LayerNorm over 1024 channels.  One block per row.
// ---------------------------------------------------------------------------
__global__ __launch_bounds__(256) void gate_k(
    const u16* __restrict__ Y, const u16* __restrict__ xBC,
    const float* __restrict__ ln_w, const float* __restrict__ ln_b,
    u16* __restrict__ yn)
{
    __shared__ float r1[4], r2[4];
    const int row = blockIdx.x;
    const int tid = threadIdx.x;
    const int lane = tid & 63, wid = tid >> 6;

    float gv[4];
    {
        const ushort4 yv = *(const ushort4*)(Y + (size_t)row * DINNER + tid * 4);
        const ushort4 zv = *(const ushort4*)(xBC + (size_t)row * NPROJ + 1024 + tid * 4);
        gv[0] = bf2f(yv.x) * silu_f(bf2f(zv.x));
        gv[1] = bf2f(yv.y) * silu_f(bf2f(zv.y));
        gv[2] = bf2f(yv.z) * silu_f(bf2f(zv.z));
        gv[3] = bf2f(yv.w) * silu_f(bf2f(zv.w));
    }
    float ps = gv[0] + gv[1] + gv[2] + gv[3];
    float pq = gv[0]*gv[0] + gv[1]*gv[1] + gv[2]*gv[2] + gv[3]*gv[3];
    #pragma unroll
    for (int off = 1; off < 64; off <<= 1) {
        ps += __shfl_xor(ps, off);
        pq += __shfl_xor(pq, off);
    }
    if (lane == 0) { r1[wid] = ps; r2[wid] = pq; }
    __syncthreads();
    float ts = r1[0] + r1[1] + r1[2] + r1[3];
    float tq = r2[0] + r2[1] + r2[2] + r2[3];
    float mu = ts * (1.0f / DINNER);
    float var = tq * (1.0f / DINNER) - mu * mu;
    float inv = rsqrtf(var + 1e-5f);

    u16 outv[4];
    #pragma unroll
    for (int j = 0; j < 4; ++j) {
        int c = tid * 4 + j;
        float v = (gv[j] - mu) * inv * ln_w[c] + ln_b[c];
        outv[j] = f2bf(v);
    }
    *(ushort4*)(yn + (size_t)row * DINNER + tid * 4) = *(ushort4*)outv;
}

// ---------------------------------------------------------------------------
extern "C" void kernel_launch(void* const* d_in, const int* in_sizes, int n_in,
                              void* d_out, int out_size, void* d_ws, size_t ws_size,
                              hipStream_t stream) {
    const float* x   = (const float*)d_in[0];
    const float* w1  = (const float*)d_in[1];
    const float* cw  = (const float*)d_in[2];
    const float* cb  = (const float*)d_in[3];
    const float* ap  = (const float*)d_in[4];
    const float* lnw = (const float*)d_in[5];
    const float* lnb = (const float*)d_in[6];
    const float* w2  = (const float*)d_in[7];
    float* out = (float*)d_out;

    // ws layout (~107 MiB):
    u16* xBC   = (u16*)d_ws;                             // MROWS x 2176
    u16* xact  = xBC + (size_t)MROWS * NPROJ;            // MROWS x 1024
    u16* x_bf  = xact;                                   // gemm1 A; dead after gemm1,
                                                         // then reused as Y buffer
    u16* w2_bf = xact + (size_t)MROWS * DINNER;          // 1024x1024
    float* l2a  = (float*)(w2_bf + (size_t)DMODEL * DINNER);  // 64
    float* apw  = l2a + 64;                              // 64x64
    float* ainv = apw + 4096;                            // 64x64
    // w1_bf (2176x1024 bf16, 4.45MB) then Sh (bf16 S/V, 33.5MB) park in d_out:
    // w1_bf dead after both gemm1 dispatches; Sh written by pass A, consumed
    // by ssd_inter before gemm2 overwrites d_out with the final output.
    u16* w1_bf = (u16*)d_out;                            // 2176x1024 bf16
    u16* Sh    = (u16*)d_out;                            // 4 x 64 x 64 x 1024 bf16

    cast_f2b<<<(MROWS * DMODEL / 8) / 256, 256, 0, stream>>>(x, x_bf, MROWS * DMODEL / 8);
    cast_f2b<<<(NPROJ * DMODEL / 8) / 256, 256, 0, stream>>>(w1, w1_bf, NPROJ * DMODEL / 8);
    cast_f2b<<<(DMODEL * DINNER / 8) / 256, 256, 0, stream>>>(w2, w2_bf, DMODEL * DINNER / 8);
    tables_k<<<1, 256, 0, stream>>>(ap, l2a, apw, ainv);

    // gemm1 split: main N=2048 (512 blocks = exactly 2 rounds) + 128-col rem
    gemm8p_k<u16, 8, 2048, NPROJ><<<8 * 64, 512, 0, stream>>>(x_bf, w1_bf, xBC);
    gemm_rem_k<<<256, 512, 0, stream>>>(x_bf, w1_bf + (size_t)2048 * GK, xBC);

    // conv fused into intra X-staging; Y -> xact (x_bf dead after gemm1)
    ssd_intra_k<<<dim3(16, NCHUNK, BATCH), 256, 0, stream>>>(cw, cb, xBC, xact, Sh, apw, ainv);
    state_scan_k<<<1024, 256, 0, stream>>>(Sh, l2a);
    ssd_inter_k<<<dim3(16, NCHUNK, BATCH), 256, 0, stream>>>(xact, xBC, Sh, apw, l2a);

    gate_k<<<MROWS, 256, 0, stream>>>(xact, xBC, lnw, lnb, xact);
    gemm8p_k<float, 4, DMODEL, DMODEL><<<4 * 64, 512, 0, stream>>>(xact, w2_bf, out);
}